// Round 1
// baseline (3807.949 us; speedup 1.0000x reference)
//
#include <hip/hip_runtime.h>

#define NNODES 50000
#define NEDGES 800000

__device__ __forceinline__ unsigned enc_f32(float f) {
    unsigned u = __float_as_uint(f);
    return (u & 0x80000000u) ? ~u : (u | 0x80000000u);
}
__device__ __forceinline__ float dec_f32(unsigned u) {
    unsigned b = (u & 0x80000000u) ? (u ^ 0x80000000u) : ~u;
    return __uint_as_float(b);
}
__device__ __forceinline__ float leaky(float x) { return x >= 0.f ? x : 0.2f * x; }

// ---------------- GEMM: Y[n x F] = X[n x 128] @ W[128 x F] ----------------
template<int F>
__global__ __launch_bounds__(256) void gemm_k(const float* __restrict__ X,
                                              const float* __restrict__ W,
                                              float* __restrict__ Y, int n) {
    constexpr int K = 128;
    constexpr int KC = 64;       // k-chunk so static LDS stays <= 64KB
    constexpr int ROWS = 32;
    __shared__ float Ws[KC * F];
    __shared__ float Xs[ROWS * K];
    const int tid = threadIdx.x;
    const int r0 = blockIdx.x * ROWS;

    for (int i = tid; i < ROWS * K; i += 256) {
        int r = i >> 7, k = i & (K - 1);
        int row = r0 + r;
        Xs[i] = (row < n) ? X[(size_t)row * K + k] : 0.f;
    }

    constexpr int CG = F / 4;        // column groups (float4 wide)
    constexpr int NRG = 256 / CG;    // row groups
    constexpr int RR = ROWS / NRG;   // rows per thread
    const int cg = tid % CG, rg = tid / CG;
    const int c0 = cg * 4;
    const int rbase = rg * RR;

    float acc[RR][4];
    #pragma unroll
    for (int r = 0; r < RR; r++)
        for (int c = 0; c < 4; c++) acc[r][c] = 0.f;

    for (int kc = 0; kc < K; kc += KC) {
        __syncthreads();
        for (int i = tid; i < KC * F; i += 256)
            Ws[i] = W[(size_t)(kc + i / F) * F + (i % F)];
        __syncthreads();
        #pragma unroll 4
        for (int k = 0; k < KC; k++) {
            float4 w4 = *(const float4*)&Ws[k * F + c0];
            #pragma unroll
            for (int r = 0; r < RR; r++) {
                float x = Xs[(rbase + r) * K + kc + k];
                acc[r][0] += x * w4.x;
                acc[r][1] += x * w4.y;
                acc[r][2] += x * w4.z;
                acc[r][3] += x * w4.w;
            }
        }
    }
    #pragma unroll
    for (int r = 0; r < RR; r++) {
        int row = r0 + rbase + r;
        if (row < n)
            *(float4*)&Y[(size_t)row * F + c0] =
                make_float4(acc[r][0], acc[r][1], acc[r][2], acc[r][3]);
    }
}

// ---------------- attention dots: el[n,h]=sum_d feat*al, er likewise -------
template<int H, int D>
__global__ void attn_dots_k(const float* __restrict__ feat,
                            const float* __restrict__ al,
                            const float* __restrict__ ar,
                            float* __restrict__ el, float* __restrict__ er) {
    constexpr int F = H * D;
    const int node = blockIdx.x;
    const int tid = threadIdx.x;            // F threads
    float v = feat[(size_t)node * F + tid];
    float a = v * al[tid];
    float b = v * ar[tid];
    #pragma unroll
    for (int off = D / 2; off; off >>= 1) {
        a += __shfl_down(a, off, D);
        b += __shfl_down(b, off, D);
    }
    if ((tid & (D - 1)) == 0) {
        int hh = tid / D;
        el[node * H + hh] = a;
        er[node * H + hh] = b;
    }
}

// ---------------- init: zero acc, zero denom, emax = enc(-inf) -------------
__global__ void init_k(float* __restrict__ acc, float* __restrict__ denom,
                       unsigned* __restrict__ emax, int nF, int nH) {
    int i = blockIdx.x * blockDim.x + threadIdx.x;
    if (i < nF) acc[i] = 0.f;
    if (i < nH) { denom[i] = 0.f; emax[i] = 0x007FFFFFu; }  // enc(-inf)
}

// ---------------- edge pass 1: segment max ---------------------------------
template<int H>
__global__ __launch_bounds__(256) void edge_max_k(const int* __restrict__ src,
                                                  const int* __restrict__ dst,
                                                  const float* __restrict__ el,
                                                  const float* __restrict__ er,
                                                  unsigned* __restrict__ emax) {
    int gid = blockIdx.x * blockDim.x + threadIdx.x;
    if (gid >= NEDGES * H) return;
    int e = gid / H, hh = gid - e * H;
    int s = src[e], d = dst[e];
    float ev = leaky(el[s * H + hh] + er[d * H + hh]);
    atomicMax(&emax[d * H + hh], enc_f32(ev));
}

// ---------------- edge pass 2: denom sum -----------------------------------
template<int H>
__global__ __launch_bounds__(256) void edge_sum_k(const int* __restrict__ src,
                                                  const int* __restrict__ dst,
                                                  const float* __restrict__ el,
                                                  const float* __restrict__ er,
                                                  const unsigned* __restrict__ emax,
                                                  float* __restrict__ denom) {
    int gid = blockIdx.x * blockDim.x + threadIdx.x;
    if (gid >= NEDGES * H) return;
    int e = gid / H, hh = gid - e * H;
    int s = src[e], d = dst[e];
    float ev = leaky(el[s * H + hh] + er[d * H + hh]);
    float m = dec_f32(emax[d * H + hh]);
    atomicAdd(&denom[d * H + hh], __expf(ev - m));
}

// ---------------- edge pass 3: weighted scatter-add ------------------------
template<int H, int D>
__global__ __launch_bounds__(256) void edge_agg_k(const int* __restrict__ src,
                                                  const int* __restrict__ dst,
                                                  const float* __restrict__ el,
                                                  const float* __restrict__ er,
                                                  const unsigned* __restrict__ emax,
                                                  const float* __restrict__ denom,
                                                  const float* __restrict__ feat,
                                                  float* __restrict__ acc) {
    constexpr int F = H * D;
    constexpr int Q = F / 4;   // float4 chunks per edge
    int gid = blockIdx.x * blockDim.x + threadIdx.x;
    if (gid >= NEDGES * Q) return;
    int e = gid / Q, q = gid - e * Q;
    int j = q * 4, hh = j / D;
    int s = src[e], d = dst[e];
    float ev = leaky(el[s * H + hh] + er[d * H + hh]);
    float m = dec_f32(emax[d * H + hh]);
    float alpha = __expf(ev - m) / denom[d * H + hh];
    float4 f4 = *(const float4*)&feat[(size_t)s * F + j];
    float* ap = &acc[(size_t)d * F + j];
    atomicAdd(ap + 0, f4.x * alpha);
    atomicAdd(ap + 1, f4.y * alpha);
    atomicAdd(ap + 2, f4.z * alpha);
    atomicAdd(ap + 3, f4.w * alpha);
}

// ---------------- finalize: out = [relu](acc + bias) -----------------------
template<bool RELU>
__global__ void final_k(const float* __restrict__ acc, const float* __restrict__ bias,
                        float* __restrict__ out, int total, int fmask) {
    int i = blockIdx.x * blockDim.x + threadIdx.x;
    if (i >= total) return;
    float v = acc[i] + bias[i & fmask];
    if (RELU) v = v > 0.f ? v : 0.f;
    out[i] = v;
}

extern "C" void kernel_launch(void* const* d_in, const int* in_sizes, int n_in,
                              void* d_out, int out_size, void* d_ws, size_t ws_size,
                              hipStream_t stream) {
    const float* h   = (const float*)d_in[0];
    const int*   src = (const int*)d_in[1];
    const int*   dst = (const int*)d_in[2];
    const float* W1  = (const float*)d_in[3];
    const float* al1 = (const float*)d_in[4];
    const float* ar1 = (const float*)d_in[5];
    const float* b1  = (const float*)d_in[6];
    const float* W2  = (const float*)d_in[7];
    const float* al2 = (const float*)d_in[8];
    const float* ar2 = (const float*)d_in[9];
    const float* b2  = (const float*)d_in[10];
    const float* W3  = (const float*)d_in[11];
    const float* al3 = (const float*)d_in[12];
    const float* ar3 = (const float*)d_in[13];
    const float* b3  = (const float*)d_in[14];
    float* out = (float*)d_out;

    const int n = NNODES;
    float* feat  = (float*)d_ws;                      // n*128
    float* hbuf  = feat + (size_t)n * 128;            // n*128 (h1 then h2)
    float* el    = hbuf + (size_t)n * 128;            // n*4
    float* er    = el + (size_t)n * 4;                // n*4
    float* denom = er + (size_t)n * 4;                // n*4
    unsigned* emax = (unsigned*)(denom + (size_t)n * 4); // n*4

    const int nodeBlocks = (n + 31) / 32;
    const int eH4  = (NEDGES * 4 + 255) / 256;
    const int eH1  = (NEDGES + 255) / 256;
    const int eQ32 = (NEDGES * 32 + 255) / 256;
    const int eQ16 = (NEDGES * 16 + 255) / 256;
    const int nF128 = (n * 128 + 255) / 256;
    const int nF64  = (n * 64 + 255) / 256;

    // ---------- layer 1: 128 -> 4 heads x 32, relu ----------
    gemm_k<128><<<nodeBlocks, 256, 0, stream>>>(h, W1, feat, n);
    attn_dots_k<4, 32><<<n, 128, 0, stream>>>(feat, al1, ar1, el, er);
    init_k<<<nF128, 256, 0, stream>>>(hbuf, denom, emax, n * 128, n * 4);
    edge_max_k<4><<<eH4, 256, 0, stream>>>(src, dst, el, er, emax);
    edge_sum_k<4><<<eH4, 256, 0, stream>>>(src, dst, el, er, emax, denom);
    edge_agg_k<4, 32><<<eQ32, 256, 0, stream>>>(src, dst, el, er, emax, denom, feat, hbuf);
    final_k<true><<<nF128, 256, 0, stream>>>(hbuf, b1, hbuf, n * 128, 127);

    // ---------- layer 2: 128 -> 4 heads x 32, relu ----------
    gemm_k<128><<<nodeBlocks, 256, 0, stream>>>(hbuf, W2, feat, n);
    attn_dots_k<4, 32><<<n, 128, 0, stream>>>(feat, al2, ar2, el, er);
    init_k<<<nF128, 256, 0, stream>>>(hbuf, denom, emax, n * 128, n * 4);  // h1 dead after gemm
    edge_max_k<4><<<eH4, 256, 0, stream>>>(src, dst, el, er, emax);
    edge_sum_k<4><<<eH4, 256, 0, stream>>>(src, dst, el, er, emax, denom);
    edge_agg_k<4, 32><<<eQ32, 256, 0, stream>>>(src, dst, el, er, emax, denom, feat, hbuf);
    final_k<true><<<nF128, 256, 0, stream>>>(hbuf, b2, hbuf, n * 128, 127);

    // ---------- layer 3: 128 -> 1 head x 64, no relu ----------
    gemm_k<64><<<nodeBlocks, 256, 0, stream>>>(hbuf, W3, feat, n);
    attn_dots_k<1, 64><<<n, 64, 0, stream>>>(feat, al3, ar3, el, er);
    init_k<<<nF64, 256, 0, stream>>>(out, denom, emax, n * 64, n);
    edge_max_k<1><<<eH1, 256, 0, stream>>>(src, dst, el, er, emax);
    edge_sum_k<1><<<eH1, 256, 0, stream>>>(src, dst, el, er, emax, denom);
    edge_agg_k<1, 64><<<eQ16, 256, 0, stream>>>(src, dst, el, er, emax, denom, feat, out);
    final_k<false><<<nF64, 256, 0, stream>>>(out, b3, out, n * 64, 63);
}

// Round 2
// 499.076 us; speedup vs baseline: 7.6300x; 7.6300x over previous
//
#include <hip/hip_runtime.h>

#define NNODES 50000
#define NEDGES 800000

__device__ __forceinline__ float leaky(float x) { return x >= 0.f ? x : 0.2f * x; }

// ---------------- GEMM: Y[n x F] = X[n x 128] @ W[128 x F] ----------------
template<int F>
__global__ __launch_bounds__(256) void gemm_k(const float* __restrict__ X,
                                              const float* __restrict__ W,
                                              float* __restrict__ Y, int n) {
    constexpr int K = 128;
    constexpr int KC = 64;
    constexpr int ROWS = 32;
    __shared__ float Ws[KC * F];
    __shared__ float Xs[ROWS * K];
    const int tid = threadIdx.x;
    const int r0 = blockIdx.x * ROWS;

    for (int i = tid; i < ROWS * K; i += 256) {
        int r = i >> 7, k = i & (K - 1);
        int row = r0 + r;
        Xs[i] = (row < n) ? X[(size_t)row * K + k] : 0.f;
    }

    constexpr int CG = F / 4;
    constexpr int NRG = 256 / CG;
    constexpr int RR = ROWS / NRG;
    const int cg = tid % CG, rg = tid / CG;
    const int c0 = cg * 4;
    const int rbase = rg * RR;

    float acc[RR][4];
    #pragma unroll
    for (int r = 0; r < RR; r++)
        for (int c = 0; c < 4; c++) acc[r][c] = 0.f;

    for (int kc = 0; kc < K; kc += KC) {
        __syncthreads();
        for (int i = tid; i < KC * F; i += 256)
            Ws[i] = W[(size_t)(kc + i / F) * F + (i % F)];
        __syncthreads();
        #pragma unroll 4
        for (int k = 0; k < KC; k++) {
            float4 w4 = *(const float4*)&Ws[k * F + c0];
            #pragma unroll
            for (int r = 0; r < RR; r++) {
                float x = Xs[(rbase + r) * K + kc + k];
                acc[r][0] += x * w4.x;
                acc[r][1] += x * w4.y;
                acc[r][2] += x * w4.z;
                acc[r][3] += x * w4.w;
            }
        }
    }
    #pragma unroll
    for (int r = 0; r < RR; r++) {
        int row = r0 + rbase + r;
        if (row < n)
            *(float4*)&Y[(size_t)row * F + c0] =
                make_float4(acc[r][0], acc[r][1], acc[r][2], acc[r][3]);
    }
}

// ---------------- attention dots -------------------------------------------
template<int H, int D>
__global__ void attn_dots_k(const float* __restrict__ feat,
                            const float* __restrict__ al,
                            const float* __restrict__ ar,
                            float* __restrict__ el, float* __restrict__ er) {
    constexpr int F = H * D;
    const int node = blockIdx.x;
    const int tid = threadIdx.x;
    float v = feat[(size_t)node * F + tid];
    float a = v * al[tid];
    float b = v * ar[tid];
    #pragma unroll
    for (int off = D / 2; off; off >>= 1) {
        a += __shfl_down(a, off, D);
        b += __shfl_down(b, off, D);
    }
    if ((tid & (D - 1)) == 0) {
        int hh = tid / D;
        el[node * H + hh] = a;
        er[node * H + hh] = b;
    }
}

// ---------------- CSR build -------------------------------------------------
__global__ void zero_k(int* __restrict__ cnt, int n) {
    int i = blockIdx.x * blockDim.x + threadIdx.x;
    if (i < n) cnt[i] = 0;
}

__global__ void hist_k(const int* __restrict__ dst, int* __restrict__ cnt,
                       int* __restrict__ rank) {
    int e = blockIdx.x * blockDim.x + threadIdx.x;
    if (e < NEDGES) rank[e] = atomicAdd(&cnt[dst[e]], 1);
}

__global__ void scan_blk_k(const int* __restrict__ cnt, int* __restrict__ offs,
                           int* __restrict__ bsum, int n) {
    __shared__ int sm[256];
    int tid = threadIdx.x;
    int i = blockIdx.x * 256 + tid;
    int v = (i < n) ? cnt[i] : 0;
    sm[tid] = v;
    __syncthreads();
    for (int off = 1; off < 256; off <<= 1) {
        int t = (tid >= off) ? sm[tid - off] : 0;
        __syncthreads();
        sm[tid] += t;
        __syncthreads();
    }
    if (i < n) offs[i] = sm[tid] - v;          // exclusive within block
    if (tid == 255) bsum[blockIdx.x] = sm[255];
}

__global__ void scan_top_k(int* __restrict__ bsum, int nb) {
    __shared__ int sm[256];
    int tid = threadIdx.x;
    int v = (tid < nb) ? bsum[tid] : 0;
    sm[tid] = v;
    __syncthreads();
    for (int off = 1; off < 256; off <<= 1) {
        int t = (tid >= off) ? sm[tid - off] : 0;
        __syncthreads();
        sm[tid] += t;
        __syncthreads();
    }
    if (tid < nb) bsum[tid] = sm[tid] - v;     // exclusive
}

__global__ void scan_add_k(int* __restrict__ offs, const int* __restrict__ bsum, int n) {
    int i = blockIdx.x * 256 + threadIdx.x;
    if (i < n) offs[i] += bsum[blockIdx.x];
    if (i == 0) offs[n] = NEDGES;
}

__global__ void scatter_k(const int* __restrict__ src, const int* __restrict__ dst,
                          const int* __restrict__ rank, const int* __restrict__ offs,
                          int* __restrict__ esrc) {
    int e = blockIdx.x * blockDim.x + threadIdx.x;
    if (e < NEDGES) esrc[offs[dst[e]] + rank[e]] = src[e];
}

// ---------------- fused per-node softmax + aggregate, H=4 D=32 -------------
template<bool RELU>
__global__ __launch_bounds__(256) void node_agg4_k(const int* __restrict__ offs,
                                                   const int* __restrict__ esrc,
                                                   const float* __restrict__ el,
                                                   const float* __restrict__ er,
                                                   const float* __restrict__ feat,
                                                   const float* __restrict__ bias,
                                                   float* __restrict__ out) {
    int wid = (blockIdx.x * 256 + threadIdx.x) >> 6;   // node id, one wave each
    int lane = threadIdx.x & 63;
    if (wid >= NNODES) return;
    int beg = offs[wid], end = offs[wid + 1];

    int h = lane & 3;
    float erh = er[wid * 4 + h];

    // online softmax: lanes stride over edges keeping head separate
    float m = -1e30f, ssum = 0.f;
    for (int p = beg + (lane >> 2); p < end; p += 16) {
        int s = esrc[p];
        float ev = leaky(el[s * 4 + h] + erh);
        if (ev > m) { ssum = ssum * __expf(m - ev) + 1.f; m = ev; }
        else ssum += __expf(ev - m);
    }
    #pragma unroll
    for (int off = 4; off < 64; off <<= 1) {
        float m2 = __shfl_xor(m, off);
        float s2 = __shfl_xor(ssum, off);
        float mn = fmaxf(m, m2);
        ssum = ssum * __expf(m - mn) + s2 * __expf(m2 - mn);
        m = mn;
    }
    // lane L holds (m, denom) for head L&3; redistribute for column layout
    int h0 = lane >> 5;          // cols {lane, lane+64} -> heads {h0, h0+2}
    int h1 = h0 + 2;
    float m0 = __shfl(m, h0), m1 = __shfl(m, h1);
    float d0 = __shfl(ssum, h0), d1 = __shfl(ssum, h1);
    float er0 = __shfl(erh, h0), er1 = __shfl(erh, h1);
    float inv0 = d0 > 0.f ? 1.f / d0 : 0.f;
    float inv1 = d1 > 0.f ? 1.f / d1 : 0.f;

    float acc0 = 0.f, acc1 = 0.f;
    for (int p = beg; p < end; ++p) {
        int s = esrc[p];
        const float* fr = &feat[(size_t)s * 128];
        float a0 = __expf(leaky(el[s * 4 + h0] + er0) - m0) * inv0;
        float a1 = __expf(leaky(el[s * 4 + h1] + er1) - m1) * inv1;
        acc0 += fr[lane] * a0;
        acc1 += fr[64 + lane] * a1;
    }
    float v0 = acc0 + bias[lane];
    float v1 = acc1 + bias[64 + lane];
    if (RELU) { v0 = fmaxf(v0, 0.f); v1 = fmaxf(v1, 0.f); }
    out[(size_t)wid * 128 + lane] = v0;
    out[(size_t)wid * 128 + 64 + lane] = v1;
}

// ---------------- fused per-node softmax + aggregate, H=1 D=64 -------------
__global__ __launch_bounds__(256) void node_agg1_k(const int* __restrict__ offs,
                                                   const int* __restrict__ esrc,
                                                   const float* __restrict__ el,
                                                   const float* __restrict__ er,
                                                   const float* __restrict__ feat,
                                                   const float* __restrict__ bias,
                                                   float* __restrict__ out) {
    int wid = (blockIdx.x * 256 + threadIdx.x) >> 6;
    int lane = threadIdx.x & 63;
    if (wid >= NNODES) return;
    int beg = offs[wid], end = offs[wid + 1];

    float erd = er[wid];
    float m = -1e30f, ssum = 0.f;
    for (int p = beg + lane; p < end; p += 64) {
        int s = esrc[p];
        float ev = leaky(el[s] + erd);
        if (ev > m) { ssum = ssum * __expf(m - ev) + 1.f; m = ev; }
        else ssum += __expf(ev - m);
    }
    #pragma unroll
    for (int off = 1; off < 64; off <<= 1) {
        float m2 = __shfl_xor(m, off);
        float s2 = __shfl_xor(ssum, off);
        float mn = fmaxf(m, m2);
        ssum = ssum * __expf(m - mn) + s2 * __expf(m2 - mn);
        m = mn;
    }
    float inv = ssum > 0.f ? 1.f / ssum : 0.f;

    float acc = 0.f;
    for (int p = beg; p < end; ++p) {
        int s = esrc[p];
        float a = __expf(leaky(el[s] + erd) - m) * inv;
        acc += feat[(size_t)s * 64 + lane] * a;
    }
    out[(size_t)wid * 64 + lane] = acc + bias[lane];
}

extern "C" void kernel_launch(void* const* d_in, const int* in_sizes, int n_in,
                              void* d_out, int out_size, void* d_ws, size_t ws_size,
                              hipStream_t stream) {
    const float* h   = (const float*)d_in[0];
    const int*   src = (const int*)d_in[1];
    const int*   dst = (const int*)d_in[2];
    const float* W1  = (const float*)d_in[3];
    const float* al1 = (const float*)d_in[4];
    const float* ar1 = (const float*)d_in[5];
    const float* b1  = (const float*)d_in[6];
    const float* W2  = (const float*)d_in[7];
    const float* al2 = (const float*)d_in[8];
    const float* ar2 = (const float*)d_in[9];
    const float* b2  = (const float*)d_in[10];
    const float* W3  = (const float*)d_in[11];
    const float* al3 = (const float*)d_in[12];
    const float* ar3 = (const float*)d_in[13];
    const float* b3  = (const float*)d_in[14];
    float* out = (float*)d_out;

    const int n = NNODES;
    float* feat  = (float*)d_ws;                       // n*128 f32
    float* hbuf  = feat + (size_t)n * 128;             // n*128 f32
    float* el    = hbuf + (size_t)n * 128;             // n*4
    float* er    = el + (size_t)n * 4;                 // n*4
    int*   cnt   = (int*)(er + (size_t)n * 4);         // n
    int*   offs  = cnt + n;                            // n+1
    int*   esrc  = offs + (n + 1);                     // NEDGES
    int*   bsum  = esrc + NEDGES;                      // nBlk
    int*   rank  = (int*)hbuf;                         // alias: dead before hbuf written

    const int nodeBlocks = (n + 31) / 32;
    const int nBlk = (n + 255) / 256;                  // 196
    const int eBlk = (NEDGES + 255) / 256;
    const int waveBlk = (n + 3) / 4;

    // ---------- CSR build (graph shared by all 3 layers) ----------
    zero_k<<<nBlk, 256, 0, stream>>>(cnt, n);
    hist_k<<<eBlk, 256, 0, stream>>>(dst, cnt, rank);
    scan_blk_k<<<nBlk, 256, 0, stream>>>(cnt, offs, bsum, n);
    scan_top_k<<<1, 256, 0, stream>>>(bsum, nBlk);
    scan_add_k<<<nBlk, 256, 0, stream>>>(offs, bsum, n);
    scatter_k<<<eBlk, 256, 0, stream>>>(src, dst, rank, offs, esrc);

    // ---------- layer 1: 128 -> 4 heads x 32, relu ----------
    gemm_k<128><<<nodeBlocks, 256, 0, stream>>>(h, W1, feat, n);
    attn_dots_k<4, 32><<<n, 128, 0, stream>>>(feat, al1, ar1, el, er);
    node_agg4_k<true><<<waveBlk, 256, 0, stream>>>(offs, esrc, el, er, feat, b1, hbuf);

    // ---------- layer 2: 128 -> 4 heads x 32, relu ----------
    gemm_k<128><<<nodeBlocks, 256, 0, stream>>>(hbuf, W2, feat, n);
    attn_dots_k<4, 32><<<n, 128, 0, stream>>>(feat, al2, ar2, el, er);
    node_agg4_k<true><<<waveBlk, 256, 0, stream>>>(offs, esrc, el, er, feat, b2, hbuf);

    // ---------- layer 3: 128 -> 1 head x 64, no relu ----------
    gemm_k<64><<<nodeBlocks, 256, 0, stream>>>(hbuf, W3, feat, n);
    attn_dots_k<1, 64><<<n, 64, 0, stream>>>(feat, al3, ar3, el, er);
    node_agg1_k<<<waveBlk, 256, 0, stream>>>(offs, esrc, el, er, feat, b3, out);
}

// Round 3
// 423.792 us; speedup vs baseline: 8.9854x; 1.1776x over previous
//
#include <hip/hip_runtime.h>

#define NNODES 50000
#define NEDGES 800000

__device__ __forceinline__ float leaky(float x) { return x >= 0.f ? x : 0.2f * x; }

// ---------------- GEMM: Y[n x F] = X[n x 128] @ W[128 x F] ----------------
template<int F>
__global__ __launch_bounds__(256) void gemm_k(const float* __restrict__ X,
                                              const float* __restrict__ W,
                                              float* __restrict__ Y, int n) {
    constexpr int K = 128;
    constexpr int KC = 64;
    constexpr int ROWS = 32;
    __shared__ float Ws[KC * F];
    __shared__ float Xs[ROWS * K];
    const int tid = threadIdx.x;
    const int r0 = blockIdx.x * ROWS;

    for (int i = tid; i < ROWS * K; i += 256) {
        int r = i >> 7, k = i & (K - 1);
        int row = r0 + r;
        Xs[i] = (row < n) ? X[(size_t)row * K + k] : 0.f;
    }

    constexpr int CG = F / 4;
    constexpr int NRG = 256 / CG;
    constexpr int RR = ROWS / NRG;
    const int cg = tid % CG, rg = tid / CG;
    const int c0 = cg * 4;
    const int rbase = rg * RR;

    float acc[RR][4];
    #pragma unroll
    for (int r = 0; r < RR; r++)
        for (int c = 0; c < 4; c++) acc[r][c] = 0.f;

    for (int kc = 0; kc < K; kc += KC) {
        __syncthreads();
        for (int i = tid; i < KC * F; i += 256)
            Ws[i] = W[(size_t)(kc + i / F) * F + (i % F)];
        __syncthreads();
        #pragma unroll 4
        for (int k = 0; k < KC; k++) {
            float4 w4 = *(const float4*)&Ws[k * F + c0];
            #pragma unroll
            for (int r = 0; r < RR; r++) {
                float x = Xs[(rbase + r) * K + kc + k];
                acc[r][0] += x * w4.x;
                acc[r][1] += x * w4.y;
                acc[r][2] += x * w4.z;
                acc[r][3] += x * w4.w;
            }
        }
    }
    #pragma unroll
    for (int r = 0; r < RR; r++) {
        int row = r0 + rbase + r;
        if (row < n)
            *(float4*)&Y[(size_t)row * F + c0] =
                make_float4(acc[r][0], acc[r][1], acc[r][2], acc[r][3]);
    }
}

// ---------------- attention dots -------------------------------------------
template<int H, int D>
__global__ void attn_dots_k(const float* __restrict__ feat,
                            const float* __restrict__ al,
                            const float* __restrict__ ar,
                            float* __restrict__ el, float* __restrict__ er) {
    constexpr int F = H * D;
    const int node = blockIdx.x;
    const int tid = threadIdx.x;
    float v = feat[(size_t)node * F + tid];
    float a = v * al[tid];
    float b = v * ar[tid];
    #pragma unroll
    for (int off = D / 2; off; off >>= 1) {
        a += __shfl_down(a, off, D);
        b += __shfl_down(b, off, D);
    }
    if ((tid & (D - 1)) == 0) {
        int hh = tid / D;
        el[node * H + hh] = a;
        er[node * H + hh] = b;
    }
}

// ---------------- CSR build -------------------------------------------------
__global__ void zero_k(int* __restrict__ cnt, int n) {
    int i = blockIdx.x * blockDim.x + threadIdx.x;
    if (i < n) cnt[i] = 0;
}

__global__ void hist_k(const int* __restrict__ dst, int* __restrict__ cnt,
                       int* __restrict__ rank) {
    int e = blockIdx.x * blockDim.x + threadIdx.x;
    if (e < NEDGES) rank[e] = atomicAdd(&cnt[dst[e]], 1);
}

__global__ void scan_blk_k(const int* __restrict__ cnt, int* __restrict__ offs,
                           int* __restrict__ bsum, int n) {
    __shared__ int sm[256];
    int tid = threadIdx.x;
    int i = blockIdx.x * 256 + tid;
    int v = (i < n) ? cnt[i] : 0;
    sm[tid] = v;
    __syncthreads();
    for (int off = 1; off < 256; off <<= 1) {
        int t = (tid >= off) ? sm[tid - off] : 0;
        __syncthreads();
        sm[tid] += t;
        __syncthreads();
    }
    if (i < n) offs[i] = sm[tid] - v;
    if (tid == 255) bsum[blockIdx.x] = sm[255];
}

__global__ void scan_top_k(int* __restrict__ bsum, int nb) {
    __shared__ int sm[256];
    int tid = threadIdx.x;
    int v = (tid < nb) ? bsum[tid] : 0;
    sm[tid] = v;
    __syncthreads();
    for (int off = 1; off < 256; off <<= 1) {
        int t = (tid >= off) ? sm[tid - off] : 0;
        __syncthreads();
        sm[tid] += t;
        __syncthreads();
    }
    if (tid < nb) bsum[tid] = sm[tid] - v;
}

__global__ void scan_add_k(int* __restrict__ offs, const int* __restrict__ bsum, int n) {
    int i = blockIdx.x * 256 + threadIdx.x;
    if (i < n) offs[i] += bsum[blockIdx.x];
    if (i == 0) offs[n] = NEDGES;
}

__global__ void scatter_k(const int* __restrict__ src, const int* __restrict__ dst,
                          const int* __restrict__ rank, const int* __restrict__ offs,
                          int* __restrict__ esrc) {
    int e = blockIdx.x * blockDim.x + threadIdx.x;
    if (e < NEDGES) esrc[offs[dst[e]] + rank[e]] = src[e];
}

// ---------------- fused per-node softmax + aggregate, H=4 D=32 -------------
// One wave per node. Phase 1: online softmax (per-head lanes). Phase 2:
// 16-edge chunks; 64 lanes compute the 16x4 alphas ONCE, broadcast by shfl;
// each lane accumulates cols (2*lane, 2*lane+1) with a dwordx2 gather.
template<bool RELU>
__global__ __launch_bounds__(256) void node_agg4_k(const int* __restrict__ offs,
                                                   const int* __restrict__ esrc,
                                                   const float* __restrict__ el,
                                                   const float* __restrict__ er,
                                                   const float* __restrict__ feat,
                                                   const float* __restrict__ bias,
                                                   float* __restrict__ out) {
    int wid = (blockIdx.x * 256 + threadIdx.x) >> 6;
    int lane = threadIdx.x & 63;
    if (wid >= NNODES) return;
    int beg = offs[wid], end = offs[wid + 1];

    const int h = lane & 3;          // head owned in softmax/alpha phases
    const int hc = lane >> 4;        // head of column pair (2*lane, 2*lane+1)
    float erh = er[wid * 4 + h];

    // phase 1: online softmax, 16 edge-slots x 4 heads
    float m = -1e30f, ssum = 0.f;
    for (int p = beg + (lane >> 2); p < end; p += 16) {
        int s = esrc[p];
        float ev = leaky(el[s * 4 + h] + erh);
        if (ev > m) { ssum = ssum * __expf(m - ev) + 1.f; m = ev; }
        else ssum += __expf(ev - m);
    }
    #pragma unroll
    for (int off = 4; off < 64; off <<= 1) {
        float m2 = __shfl_xor(m, off);
        float s2 = __shfl_xor(ssum, off);
        float mn = fmaxf(m, m2);
        ssum = ssum * __expf(m - mn) + s2 * __expf(m2 - mn);
        m = mn;
    }
    float inv = ssum > 0.f ? 1.f / ssum : 0.f;

    // phase 2: chunks of 16 edges
    float accx = 0.f, accy = 0.f;
    for (int base = beg; base < end; base += 16) {
        int rem = end - base;
        if (rem > 16) rem = 16;
        int sv = 0;
        if (lane < rem) sv = esrc[base + lane];         // lanes 0..rem-1 hold srcs
        int se = __shfl(sv, lane >> 2);                 // src of my (edge,head)
        float av = 0.f;
        if ((lane >> 2) < rem)
            av = __expf(leaky(el[se * 4 + h] + erh) - m) * inv;
        #pragma unroll 4
        for (int e = 0; e < rem; e++) {
            int s = __shfl(sv, e);
            float a = __shfl(av, e * 4 + hc);
            float2 f2 = *(const float2*)&feat[(size_t)s * 128 + 2 * lane];
            accx += f2.x * a;
            accy += f2.y * a;
        }
    }
    float2 b2 = *(const float2*)&bias[2 * lane];
    float vx = accx + b2.x, vy = accy + b2.y;
    if (RELU) { vx = fmaxf(vx, 0.f); vy = fmaxf(vy, 0.f); }
    *(float2*)&out[(size_t)wid * 128 + 2 * lane] = make_float2(vx, vy);
}

// ---------------- fused per-node softmax + aggregate, H=1 D=64 -------------
__global__ __launch_bounds__(256) void node_agg1_k(const int* __restrict__ offs,
                                                   const int* __restrict__ esrc,
                                                   const float* __restrict__ el,
                                                   const float* __restrict__ er,
                                                   const float* __restrict__ feat,
                                                   const float* __restrict__ bias,
                                                   float* __restrict__ out) {
    int wid = (blockIdx.x * 256 + threadIdx.x) >> 6;
    int lane = threadIdx.x & 63;
    if (wid >= NNODES) return;
    int beg = offs[wid], end = offs[wid + 1];

    float erd = er[wid];
    float m = -1e30f, ssum = 0.f;
    for (int p = beg + lane; p < end; p += 64) {
        int s = esrc[p];
        float ev = leaky(el[s] + erd);
        if (ev > m) { ssum = ssum * __expf(m - ev) + 1.f; m = ev; }
        else ssum += __expf(ev - m);
    }
    #pragma unroll
    for (int off = 1; off < 64; off <<= 1) {
        float m2 = __shfl_xor(m, off);
        float s2 = __shfl_xor(ssum, off);
        float mn = fmaxf(m, m2);
        ssum = ssum * __expf(m - mn) + s2 * __expf(m2 - mn);
        m = mn;
    }
    float inv = ssum > 0.f ? 1.f / ssum : 0.f;

    float acc = 0.f;
    for (int base = beg; base < end; base += 64) {
        int rem = end - base;
        if (rem > 64) rem = 64;
        int sv = 0;
        float av = 0.f;
        if (lane < rem) {
            sv = esrc[base + lane];
            av = __expf(leaky(el[sv] + erd) - m) * inv;
        }
        #pragma unroll 4
        for (int e = 0; e < rem; e++) {
            int s = __shfl(sv, e);
            float a = __shfl(av, e);
            acc += feat[(size_t)s * 64 + lane] * a;
        }
    }
    out[(size_t)wid * 64 + lane] = acc + bias[lane];
}

extern "C" void kernel_launch(void* const* d_in, const int* in_sizes, int n_in,
                              void* d_out, int out_size, void* d_ws, size_t ws_size,
                              hipStream_t stream) {
    const float* h   = (const float*)d_in[0];
    const int*   src = (const int*)d_in[1];
    const int*   dst = (const int*)d_in[2];
    const float* W1  = (const float*)d_in[3];
    const float* al1 = (const float*)d_in[4];
    const float* ar1 = (const float*)d_in[5];
    const float* b1  = (const float*)d_in[6];
    const float* W2  = (const float*)d_in[7];
    const float* al2 = (const float*)d_in[8];
    const float* ar2 = (const float*)d_in[9];
    const float* b2  = (const float*)d_in[10];
    const float* W3  = (const float*)d_in[11];
    const float* al3 = (const float*)d_in[12];
    const float* ar3 = (const float*)d_in[13];
    const float* b3  = (const float*)d_in[14];
    float* out = (float*)d_out;

    const int n = NNODES;
    float* feat  = (float*)d_ws;                       // n*128 f32
    float* hbuf  = feat + (size_t)n * 128;             // n*128 f32
    float* el    = hbuf + (size_t)n * 128;             // n*4
    float* er    = el + (size_t)n * 4;                 // n*4
    int*   cnt   = (int*)(er + (size_t)n * 4);         // n
    int*   offs  = cnt + n;                            // n+1
    int*   esrc  = offs + (n + 1);                     // NEDGES
    int*   bsum  = esrc + NEDGES;                      // nBlk
    int*   rank  = (int*)hbuf;                         // alias: dead before hbuf written

    const int nodeBlocks = (n + 31) / 32;
    const int nBlk = (n + 255) / 256;
    const int eBlk = (NEDGES + 255) / 256;
    const int waveBlk = (n + 3) / 4;

    // ---------- CSR build (graph shared by all 3 layers) ----------
    zero_k<<<nBlk, 256, 0, stream>>>(cnt, n);
    hist_k<<<eBlk, 256, 0, stream>>>(dst, cnt, rank);
    scan_blk_k<<<nBlk, 256, 0, stream>>>(cnt, offs, bsum, n);
    scan_top_k<<<1, 256, 0, stream>>>(bsum, nBlk);
    scan_add_k<<<nBlk, 256, 0, stream>>>(offs, bsum, n);
    scatter_k<<<eBlk, 256, 0, stream>>>(src, dst, rank, offs, esrc);

    // ---------- layer 1: 128 -> 4 heads x 32, relu ----------
    gemm_k<128><<<nodeBlocks, 256, 0, stream>>>(h, W1, feat, n);
    attn_dots_k<4, 32><<<n, 128, 0, stream>>>(feat, al1, ar1, el, er);
    node_agg4_k<true><<<waveBlk, 256, 0, stream>>>(offs, esrc, el, er, feat, b1, hbuf);

    // ---------- layer 2: 128 -> 4 heads x 32, relu ----------
    gemm_k<128><<<nodeBlocks, 256, 0, stream>>>(hbuf, W2, feat, n);
    attn_dots_k<4, 32><<<n, 128, 0, stream>>>(feat, al2, ar2, el, er);
    node_agg4_k<true><<<waveBlk, 256, 0, stream>>>(offs, esrc, el, er, feat, b2, hbuf);

    // ---------- layer 3: 128 -> 1 head x 64, no relu ----------
    gemm_k<64><<<nodeBlocks, 256, 0, stream>>>(hbuf, W3, feat, n);
    attn_dots_k<1, 64><<<n, 64, 0, stream>>>(feat, al3, ar3, el, er);
    node_agg1_k<<<waveBlk, 256, 0, stream>>>(offs, esrc, el, er, feat, b3, out);
}

// Round 4
// 371.756 us; speedup vs baseline: 10.2432x; 1.1400x over previous
//
#include <hip/hip_runtime.h>

#define NNODES 50000
#define NEDGES 800000

__device__ __forceinline__ float leaky(float x) { return x >= 0.f ? x : 0.2f * x; }

// ---- fused GEMM + attention dots ------------------------------------------
// Y[n x F] = X[n x 128] @ W[128 x F]; el/er[n x H] = per-head dots with al/ar.
// Block: 64 rows x F cols, 256 threads. Thread: 4 rows x 8 cols, the 8 cols
// split as two float4 blocks at {cg*4, F/2+cg*4} (bank-conflict-free Ws reads).
template<int F, int H>
__global__ __launch_bounds__(256) void gemm_dots_k(const float* __restrict__ X,
                                                   const float* __restrict__ W,
                                                   const float* __restrict__ al,
                                                   const float* __restrict__ ar,
                                                   float* __restrict__ Y,
                                                   float* __restrict__ el,
                                                   float* __restrict__ er, int n) {
    constexpr int K = 128;
    constexpr int KC = 64;
    constexpr int ROWS = 64;
    constexpr int CG = F / 8;            // column-group threads (16 or 8)
    constexpr int RR = ROWS / (256 / CG); // rows per thread (4 for F=128, 2 for F=64)
    __shared__ float Ws[KC * F];
    __shared__ float Xs[ROWS * KC];

    const int tid = threadIdx.x;
    const int cg = tid % CG, rg = tid / CG;
    const int c0a = cg * 4, c0b = F / 2 + cg * 4;
    const int rbase = rg * RR;
    const int r0 = blockIdx.x * ROWS;

    float acca[RR][4], accb[RR][4];
    #pragma unroll
    for (int r = 0; r < RR; r++)
        #pragma unroll
        for (int c = 0; c < 4; c++) { acca[r][c] = 0.f; accb[r][c] = 0.f; }

    for (int kc = 0; kc < K; kc += KC) {
        __syncthreads();
        // stage W chunk: contiguous copy of KC*F floats
        {
            const float4* W4 = (const float4*)(W + (size_t)kc * F);
            float4* Ws4 = (float4*)Ws;
            #pragma unroll
            for (int i = tid; i < KC * F / 4; i += 256) Ws4[i] = W4[i];
        }
        // stage X chunk: 64 rows x KC floats
        {
            float4* Xs4 = (float4*)Xs;
            #pragma unroll
            for (int i = tid; i < ROWS * (KC / 4); i += 256) {
                int r = i / (KC / 4), q = i % (KC / 4);
                int row = r0 + r;
                Xs4[i] = (row < n) ? ((const float4*)X)[(size_t)row * (K / 4) + kc / 4 + q]
                                   : make_float4(0.f, 0.f, 0.f, 0.f);
            }
        }
        __syncthreads();
        #pragma unroll 4
        for (int k = 0; k < KC; k++) {
            float4 wa = *(const float4*)&Ws[k * F + c0a];
            float4 wb = *(const float4*)&Ws[k * F + c0b];
            #pragma unroll
            for (int r = 0; r < RR; r++) {
                float x = Xs[(rbase + r) * KC + k];
                acca[r][0] += x * wa.x; acca[r][1] += x * wa.y;
                acca[r][2] += x * wa.z; acca[r][3] += x * wa.w;
                accb[r][0] += x * wb.x; accb[r][1] += x * wb.y;
                accb[r][2] += x * wb.z; accb[r][3] += x * wb.w;
            }
        }
    }

    // store Y
    #pragma unroll
    for (int r = 0; r < RR; r++) {
        int row = r0 + rbase + r;
        if (row < n) {
            *(float4*)&Y[(size_t)row * F + c0a] =
                make_float4(acca[r][0], acca[r][1], acca[r][2], acca[r][3]);
            *(float4*)&Y[(size_t)row * F + c0b] =
                make_float4(accb[r][0], accb[r][1], accb[r][2], accb[r][3]);
        }
    }

    // fused attention dots: el/er[row, head] = sum_d feat*al / feat*ar
    float4 ala = *(const float4*)&al[c0a];
    float4 alb = *(const float4*)&al[c0b];
    float4 ara = *(const float4*)&ar[c0a];
    float4 arb = *(const float4*)&ar[c0b];
    #pragma unroll
    for (int r = 0; r < RR; r++) {
        float pla = acca[r][0]*ala.x + acca[r][1]*ala.y + acca[r][2]*ala.z + acca[r][3]*ala.w;
        float plb = accb[r][0]*alb.x + accb[r][1]*alb.y + accb[r][2]*alb.z + accb[r][3]*alb.w;
        float pra = acca[r][0]*ara.x + acca[r][1]*ara.y + acca[r][2]*ara.z + acca[r][3]*ara.w;
        float prb = accb[r][0]*arb.x + accb[r][1]*arb.y + accb[r][2]*arb.z + accb[r][3]*arb.w;
        if (H == 1) { pla += plb; pra += prb; }
        // reduce across the 8 threads sharing (row, head): lanes aligned mod 8
        #pragma unroll
        for (int off = 1; off < 8; off <<= 1) {
            pla += __shfl_xor(pla, off);
            pra += __shfl_xor(pra, off);
            if (H > 1) { plb += __shfl_xor(plb, off); prb += __shfl_xor(prb, off); }
        }
        int row = r0 + rbase + r;
        if ((cg & 7) == 0 && row < n) {
            if (H == 1) {
                el[row] = pla; er[row] = pra;
            } else {
                int hd = cg / 8;               // 0 or 1 for block a; +2 for block b
                el[row * H + hd] = pla;     er[row * H + hd] = pra;
                el[row * H + hd + 2] = plb; er[row * H + hd + 2] = prb;
            }
        }
    }
}

// ---------------- CSR build -------------------------------------------------
__global__ void zero_k(int* __restrict__ cnt, int n) {
    int i = blockIdx.x * blockDim.x + threadIdx.x;
    if (i < n) cnt[i] = 0;
}

__global__ void hist_k(const int* __restrict__ dst, int* __restrict__ cnt,
                       int* __restrict__ rank) {
    int e = blockIdx.x * blockDim.x + threadIdx.x;
    if (e < NEDGES) rank[e] = atomicAdd(&cnt[dst[e]], 1);
}

__global__ void scan_blk_k(const int* __restrict__ cnt, int* __restrict__ offs,
                           int* __restrict__ bsum, int n) {
    __shared__ int sm[256];
    int tid = threadIdx.x;
    int i = blockIdx.x * 256 + tid;
    int v = (i < n) ? cnt[i] : 0;
    sm[tid] = v;
    __syncthreads();
    for (int off = 1; off < 256; off <<= 1) {
        int t = (tid >= off) ? sm[tid - off] : 0;
        __syncthreads();
        sm[tid] += t;
        __syncthreads();
    }
    if (i < n) offs[i] = sm[tid] - v;
    if (tid == 255) bsum[blockIdx.x] = sm[255];
}

__global__ void scan_top_k(int* __restrict__ bsum, int nb) {
    __shared__ int sm[256];
    int tid = threadIdx.x;
    int v = (tid < nb) ? bsum[tid] : 0;
    sm[tid] = v;
    __syncthreads();
    for (int off = 1; off < 256; off <<= 1) {
        int t = (tid >= off) ? sm[tid - off] : 0;
        __syncthreads();
        sm[tid] += t;
        __syncthreads();
    }
    if (tid < nb) bsum[tid] = sm[tid] - v;
}

__global__ void scan_add_k(int* __restrict__ offs, const int* __restrict__ bsum, int n) {
    int i = blockIdx.x * 256 + threadIdx.x;
    if (i < n) offs[i] += bsum[blockIdx.x];
    if (i == 0) offs[n] = NEDGES;
}

__global__ void scatter_k(const int* __restrict__ src, const int* __restrict__ dst,
                          const int* __restrict__ rank, const int* __restrict__ offs,
                          int* __restrict__ esrc) {
    int e = blockIdx.x * blockDim.x + threadIdx.x;
    if (e < NEDGES) esrc[offs[dst[e]] + rank[e]] = src[e];
}

// ---------------- fused per-node softmax + aggregate, H=4 D=32 -------------
template<bool RELU>
__global__ __launch_bounds__(256) void node_agg4_k(const int* __restrict__ offs,
                                                   const int* __restrict__ esrc,
                                                   const float* __restrict__ el,
                                                   const float* __restrict__ er,
                                                   const float* __restrict__ feat,
                                                   const float* __restrict__ bias,
                                                   float* __restrict__ out) {
    int wid = (blockIdx.x * 256 + threadIdx.x) >> 6;
    int lane = threadIdx.x & 63;
    if (wid >= NNODES) return;
    int beg = offs[wid], end = offs[wid + 1];

    const int h = lane & 3;
    const int hc = lane >> 4;
    float erh = er[wid * 4 + h];

    float m = -1e30f, ssum = 0.f;
    for (int p = beg + (lane >> 2); p < end; p += 16) {
        int s = esrc[p];
        float ev = leaky(el[s * 4 + h] + erh);
        if (ev > m) { ssum = ssum * __expf(m - ev) + 1.f; m = ev; }
        else ssum += __expf(ev - m);
    }
    #pragma unroll
    for (int off = 4; off < 64; off <<= 1) {
        float m2 = __shfl_xor(m, off);
        float s2 = __shfl_xor(ssum, off);
        float mn = fmaxf(m, m2);
        ssum = ssum * __expf(m - mn) + s2 * __expf(m2 - mn);
        m = mn;
    }
    float inv = ssum > 0.f ? 1.f / ssum : 0.f;

    float accx = 0.f, accy = 0.f;
    for (int base = beg; base < end; base += 16) {
        int rem = end - base;
        if (rem > 16) rem = 16;
        int sv = 0;
        if (lane < rem) sv = esrc[base + lane];
        int se = __shfl(sv, lane >> 2);
        float av = 0.f;
        if ((lane >> 2) < rem)
            av = __expf(leaky(el[se * 4 + h] + erh) - m) * inv;
        #pragma unroll 4
        for (int e = 0; e < rem; e++) {
            int s = __shfl(sv, e);
            float a = __shfl(av, e * 4 + hc);
            float2 f2 = *(const float2*)&feat[(size_t)s * 128 + 2 * lane];
            accx += f2.x * a;
            accy += f2.y * a;
        }
    }
    float2 b2 = *(const float2*)&bias[2 * lane];
    float vx = accx + b2.x, vy = accy + b2.y;
    if (RELU) { vx = fmaxf(vx, 0.f); vy = fmaxf(vy, 0.f); }
    *(float2*)&out[(size_t)wid * 128 + 2 * lane] = make_float2(vx, vy);
}

// ---------------- fused per-node softmax + aggregate, H=1 D=64 -------------
__global__ __launch_bounds__(256) void node_agg1_k(const int* __restrict__ offs,
                                                   const int* __restrict__ esrc,
                                                   const float* __restrict__ el,
                                                   const float* __restrict__ er,
                                                   const float* __restrict__ feat,
                                                   const float* __restrict__ bias,
                                                   float* __restrict__ out) {
    int wid = (blockIdx.x * 256 + threadIdx.x) >> 6;
    int lane = threadIdx.x & 63;
    if (wid >= NNODES) return;
    int beg = offs[wid], end = offs[wid + 1];

    float erd = er[wid];
    float m = -1e30f, ssum = 0.f;
    for (int p = beg + lane; p < end; p += 64) {
        int s = esrc[p];
        float ev = leaky(el[s] + erd);
        if (ev > m) { ssum = ssum * __expf(m - ev) + 1.f; m = ev; }
        else ssum += __expf(ev - m);
    }
    #pragma unroll
    for (int off = 1; off < 64; off <<= 1) {
        float m2 = __shfl_xor(m, off);
        float s2 = __shfl_xor(ssum, off);
        float mn = fmaxf(m, m2);
        ssum = ssum * __expf(m - mn) + s2 * __expf(m2 - mn);
        m = mn;
    }
    float inv = ssum > 0.f ? 1.f / ssum : 0.f;

    float acc = 0.f;
    for (int base = beg; base < end; base += 64) {
        int rem = end - base;
        if (rem > 64) rem = 64;
        int sv = 0;
        float av = 0.f;
        if (lane < rem) {
            sv = esrc[base + lane];
            av = __expf(leaky(el[sv] + erd) - m) * inv;
        }
        #pragma unroll 4
        for (int e = 0; e < rem; e++) {
            int s = __shfl(sv, e);
            float a = __shfl(av, e);
            acc += feat[(size_t)s * 64 + lane] * a;
        }
    }
    out[(size_t)wid * 64 + lane] = acc + bias[lane];
}

extern "C" void kernel_launch(void* const* d_in, const int* in_sizes, int n_in,
                              void* d_out, int out_size, void* d_ws, size_t ws_size,
                              hipStream_t stream) {
    const float* h   = (const float*)d_in[0];
    const int*   src = (const int*)d_in[1];
    const int*   dst = (const int*)d_in[2];
    const float* W1  = (const float*)d_in[3];
    const float* al1 = (const float*)d_in[4];
    const float* ar1 = (const float*)d_in[5];
    const float* b1  = (const float*)d_in[6];
    const float* W2  = (const float*)d_in[7];
    const float* al2 = (const float*)d_in[8];
    const float* ar2 = (const float*)d_in[9];
    const float* b2  = (const float*)d_in[10];
    const float* W3  = (const float*)d_in[11];
    const float* al3 = (const float*)d_in[12];
    const float* ar3 = (const float*)d_in[13];
    const float* b3  = (const float*)d_in[14];
    float* out = (float*)d_out;

    const int n = NNODES;
    float* feat  = (float*)d_ws;                       // n*128 f32
    float* hbuf  = feat + (size_t)n * 128;             // n*128 f32
    float* el    = hbuf + (size_t)n * 128;             // n*4
    float* er    = el + (size_t)n * 4;                 // n*4
    int*   cnt   = (int*)(er + (size_t)n * 4);         // n
    int*   offs  = cnt + n;                            // n+1
    int*   esrc  = offs + (n + 1);                     // NEDGES
    int*   bsum  = esrc + NEDGES;                      // nBlk
    int*   rank  = (int*)hbuf;                         // alias: dead before hbuf written

    const int gemmBlocks = (n + 63) / 64;
    const int nBlk = (n + 255) / 256;
    const int eBlk = (NEDGES + 255) / 256;
    const int waveBlk = (n + 3) / 4;

    // ---------- CSR build (graph shared by all 3 layers) ----------
    zero_k<<<nBlk, 256, 0, stream>>>(cnt, n);
    hist_k<<<eBlk, 256, 0, stream>>>(dst, cnt, rank);
    scan_blk_k<<<nBlk, 256, 0, stream>>>(cnt, offs, bsum, n);
    scan_top_k<<<1, 256, 0, stream>>>(bsum, nBlk);
    scan_add_k<<<nBlk, 256, 0, stream>>>(offs, bsum, n);
    scatter_k<<<eBlk, 256, 0, stream>>>(src, dst, rank, offs, esrc);

    // ---------- layer 1: 128 -> 4 heads x 32, relu ----------
    gemm_dots_k<128, 4><<<gemmBlocks, 256, 0, stream>>>(h, W1, al1, ar1, feat, el, er, n);
    node_agg4_k<true><<<waveBlk, 256, 0, stream>>>(offs, esrc, el, er, feat, b1, hbuf);

    // ---------- layer 2: 128 -> 4 heads x 32, relu ----------
    gemm_dots_k<128, 4><<<gemmBlocks, 256, 0, stream>>>(hbuf, W2, al2, ar2, feat, el, er, n);
    node_agg4_k<true><<<waveBlk, 256, 0, stream>>>(offs, esrc, el, er, feat, b2, hbuf);

    // ---------- layer 3: 128 -> 1 head x 64, no relu ----------
    gemm_dots_k<64, 1><<<gemmBlocks, 256, 0, stream>>>(hbuf, W3, al3, ar3, feat, el, er, n);
    node_agg1_k<<<waveBlk, 256, 0, stream>>>(offs, esrc, el, er, feat, b3, out);
}

// Round 5
// 356.410 us; speedup vs baseline: 10.6842x; 1.0431x over previous
//
#include <hip/hip_runtime.h>
#include <hip/hip_fp16.h>

#define NNODES 50000
#define NEDGES 800000

__device__ __forceinline__ float leaky(float x) { return x >= 0.f ? x : 0.2f * x; }

struct __align__(8) half4v { __half2 x, y; };

// ---- fused GEMM + attention dots, fp16 feature output ----------------------
// Yh[n x F] (fp16) = X[n x 128] @ W[128 x F]; el/er[n x H] = head dots (f32).
template<int F, int H>
__global__ __launch_bounds__(256) void gemm_dots_k(const float* __restrict__ X,
                                                   const float* __restrict__ W,
                                                   const float* __restrict__ al,
                                                   const float* __restrict__ ar,
                                                   __half* __restrict__ Yh,
                                                   float* __restrict__ el,
                                                   float* __restrict__ er, int n) {
    constexpr int K = 128;
    constexpr int KC = 64;
    constexpr int ROWS = 64;
    constexpr int CG = F / 8;
    constexpr int RR = ROWS / (256 / CG);
    __shared__ float Ws[KC * F];
    __shared__ float Xs[ROWS * KC];

    const int tid = threadIdx.x;
    const int cg = tid % CG, rg = tid / CG;
    const int c0a = cg * 4, c0b = F / 2 + cg * 4;
    const int rbase = rg * RR;
    const int r0 = blockIdx.x * ROWS;

    float acca[RR][4], accb[RR][4];
    #pragma unroll
    for (int r = 0; r < RR; r++)
        #pragma unroll
        for (int c = 0; c < 4; c++) { acca[r][c] = 0.f; accb[r][c] = 0.f; }

    for (int kc = 0; kc < K; kc += KC) {
        __syncthreads();
        {
            const float4* W4 = (const float4*)(W + (size_t)kc * F);
            float4* Ws4 = (float4*)Ws;
            #pragma unroll
            for (int i = tid; i < KC * F / 4; i += 256) Ws4[i] = W4[i];
        }
        {
            float4* Xs4 = (float4*)Xs;
            #pragma unroll
            for (int i = tid; i < ROWS * (KC / 4); i += 256) {
                int r = i / (KC / 4), q = i % (KC / 4);
                int row = r0 + r;
                Xs4[i] = (row < n) ? ((const float4*)X)[(size_t)row * (K / 4) + kc / 4 + q]
                                   : make_float4(0.f, 0.f, 0.f, 0.f);
            }
        }
        __syncthreads();
        #pragma unroll 4
        for (int k = 0; k < KC; k++) {
            float4 wa = *(const float4*)&Ws[k * F + c0a];
            float4 wb = *(const float4*)&Ws[k * F + c0b];
            #pragma unroll
            for (int r = 0; r < RR; r++) {
                float x = Xs[(rbase + r) * KC + k];
                acca[r][0] += x * wa.x; acca[r][1] += x * wa.y;
                acca[r][2] += x * wa.z; acca[r][3] += x * wa.w;
                accb[r][0] += x * wb.x; accb[r][1] += x * wb.y;
                accb[r][2] += x * wb.z; accb[r][3] += x * wb.w;
            }
        }
    }

    // store fp16 feature rows
    #pragma unroll
    for (int r = 0; r < RR; r++) {
        int row = r0 + rbase + r;
        if (row < n) {
            half4v ha, hb;
            ha.x = __halves2half2(__float2half_rn(acca[r][0]), __float2half_rn(acca[r][1]));
            ha.y = __halves2half2(__float2half_rn(acca[r][2]), __float2half_rn(acca[r][3]));
            hb.x = __halves2half2(__float2half_rn(accb[r][0]), __float2half_rn(accb[r][1]));
            hb.y = __halves2half2(__float2half_rn(accb[r][2]), __float2half_rn(accb[r][3]));
            *(half4v*)&Yh[(size_t)row * F + c0a] = ha;
            *(half4v*)&Yh[(size_t)row * F + c0b] = hb;
        }
    }

    // fused attention dots (f32 accumulators)
    float4 ala = *(const float4*)&al[c0a];
    float4 alb = *(const float4*)&al[c0b];
    float4 ara = *(const float4*)&ar[c0a];
    float4 arb = *(const float4*)&ar[c0b];
    #pragma unroll
    for (int r = 0; r < RR; r++) {
        float pla = acca[r][0]*ala.x + acca[r][1]*ala.y + acca[r][2]*ala.z + acca[r][3]*ala.w;
        float plb = accb[r][0]*alb.x + accb[r][1]*alb.y + accb[r][2]*alb.z + accb[r][3]*alb.w;
        float pra = acca[r][0]*ara.x + acca[r][1]*ara.y + acca[r][2]*ara.z + acca[r][3]*ara.w;
        float prb = accb[r][0]*arb.x + accb[r][1]*arb.y + accb[r][2]*arb.z + accb[r][3]*arb.w;
        if (H == 1) { pla += plb; pra += prb; }
        #pragma unroll
        for (int off = 1; off < 8; off <<= 1) {
            pla += __shfl_xor(pla, off);
            pra += __shfl_xor(pra, off);
            if (H > 1) { plb += __shfl_xor(plb, off); prb += __shfl_xor(prb, off); }
        }
        int row = r0 + rbase + r;
        if ((cg & 7) == 0 && row < n) {
            if (H == 1) {
                el[row] = pla; er[row] = pra;
            } else {
                int hd = cg / 8;
                el[row * H + hd] = pla;     er[row * H + hd] = pra;
                el[row * H + hd + 2] = plb; er[row * H + hd + 2] = prb;
            }
        }
    }
}

// ---------------- CSR build -------------------------------------------------
__global__ void zero_k(int* __restrict__ cnt, int n) {
    int i = blockIdx.x * blockDim.x + threadIdx.x;
    if (i < n) cnt[i] = 0;
}

__global__ void hist_k(const int* __restrict__ dst, int* __restrict__ cnt,
                       int* __restrict__ rank) {
    int e = blockIdx.x * blockDim.x + threadIdx.x;
    if (e < NEDGES) rank[e] = atomicAdd(&cnt[dst[e]], 1);
}

__global__ void scan_blk_k(const int* __restrict__ cnt, int* __restrict__ offs,
                           int* __restrict__ bsum, int n) {
    __shared__ int sm[256];
    int tid = threadIdx.x;
    int i = blockIdx.x * 256 + tid;
    int v = (i < n) ? cnt[i] : 0;
    sm[tid] = v;
    __syncthreads();
    for (int off = 1; off < 256; off <<= 1) {
        int t = (tid >= off) ? sm[tid - off] : 0;
        __syncthreads();
        sm[tid] += t;
        __syncthreads();
    }
    if (i < n) offs[i] = sm[tid] - v;
    if (tid == 255) bsum[blockIdx.x] = sm[255];
}

__global__ void scan_top_k(int* __restrict__ bsum, int nb) {
    __shared__ int sm[256];
    int tid = threadIdx.x;
    int v = (tid < nb) ? bsum[tid] : 0;
    sm[tid] = v;
    __syncthreads();
    for (int off = 1; off < 256; off <<= 1) {
        int t = (tid >= off) ? sm[tid - off] : 0;
        __syncthreads();
        sm[tid] += t;
        __syncthreads();
    }
    if (tid < nb) bsum[tid] = sm[tid] - v;
}

__global__ void scan_add_k(int* __restrict__ offs, const int* __restrict__ bsum, int n) {
    int i = blockIdx.x * 256 + threadIdx.x;
    if (i < n) offs[i] += bsum[blockIdx.x];
    if (i == 0) offs[n] = NEDGES;
}

__global__ void scatter_k(const int* __restrict__ src, const int* __restrict__ dst,
                          const int* __restrict__ rank, const int* __restrict__ offs,
                          int* __restrict__ esrc) {
    int e = blockIdx.x * blockDim.x + threadIdx.x;
    if (e < NEDGES) esrc[offs[dst[e]] + rank[e]] = src[e];
}

// ---------------- fused per-node softmax + aggregate, H=4 D=32 -------------
template<bool RELU>
__global__ __launch_bounds__(256) void node_agg4_k(const int* __restrict__ offs,
                                                   const int* __restrict__ esrc,
                                                   const float* __restrict__ el,
                                                   const float* __restrict__ er,
                                                   const __half* __restrict__ feat,
                                                   const float* __restrict__ bias,
                                                   float* __restrict__ out) {
    int wid = (blockIdx.x * 256 + threadIdx.x) >> 6;
    int lane = threadIdx.x & 63;
    if (wid >= NNODES) return;
    int beg = offs[wid], end = offs[wid + 1];

    const int h = lane & 3;
    const int hc = lane >> 4;
    float erh = er[wid * 4 + h];

    float m = -1e30f, ssum = 0.f;
    for (int p = beg + (lane >> 2); p < end; p += 16) {
        int s = esrc[p];
        float ev = leaky(el[s * 4 + h] + erh);
        if (ev > m) { ssum = ssum * __expf(m - ev) + 1.f; m = ev; }
        else ssum += __expf(ev - m);
    }
    #pragma unroll
    for (int off = 4; off < 64; off <<= 1) {
        float m2 = __shfl_xor(m, off);
        float s2 = __shfl_xor(ssum, off);
        float mn = fmaxf(m, m2);
        ssum = ssum * __expf(m - mn) + s2 * __expf(m2 - mn);
        m = mn;
    }
    float inv = ssum > 0.f ? 1.f / ssum : 0.f;

    float accx = 0.f, accy = 0.f;
    for (int base = beg; base < end; base += 16) {
        int rem = end - base;
        if (rem > 16) rem = 16;
        int sv = 0;
        if (lane < rem) sv = esrc[base + lane];
        int se = __shfl(sv, lane >> 2);
        float av = 0.f;
        if ((lane >> 2) < rem)
            av = __expf(leaky(el[se * 4 + h] + erh) - m) * inv;
        #pragma unroll 4
        for (int e = 0; e < rem; e++) {
            int s = __shfl(sv, e);
            float a = __shfl(av, e * 4 + hc);
            __half2 f2 = ((const __half2*)feat)[(size_t)s * 64 + lane];
            float2 ff = __half22float2(f2);
            accx += ff.x * a;
            accy += ff.y * a;
        }
    }
    float2 b2 = *(const float2*)&bias[2 * lane];
    float vx = accx + b2.x, vy = accy + b2.y;
    if (RELU) { vx = fmaxf(vx, 0.f); vy = fmaxf(vy, 0.f); }
    *(float2*)&out[(size_t)wid * 128 + 2 * lane] = make_float2(vx, vy);
}

// ---------------- fused per-node softmax + aggregate, H=1 D=64 -------------
__global__ __launch_bounds__(256) void node_agg1_k(const int* __restrict__ offs,
                                                   const int* __restrict__ esrc,
                                                   const float* __restrict__ el,
                                                   const float* __restrict__ er,
                                                   const __half* __restrict__ feat,
                                                   const float* __restrict__ bias,
                                                   float* __restrict__ out) {
    int wid = (blockIdx.x * 256 + threadIdx.x) >> 6;
    int lane = threadIdx.x & 63;
    if (wid >= NNODES) return;
    int beg = offs[wid], end = offs[wid + 1];

    float erd = er[wid];
    float m = -1e30f, ssum = 0.f;
    for (int p = beg + lane; p < end; p += 64) {
        int s = esrc[p];
        float ev = leaky(el[s] + erd);
        if (ev > m) { ssum = ssum * __expf(m - ev) + 1.f; m = ev; }
        else ssum += __expf(ev - m);
    }
    #pragma unroll
    for (int off = 1; off < 64; off <<= 1) {
        float m2 = __shfl_xor(m, off);
        float s2 = __shfl_xor(ssum, off);
        float mn = fmaxf(m, m2);
        ssum = ssum * __expf(m - mn) + s2 * __expf(m2 - mn);
        m = mn;
    }
    float inv = ssum > 0.f ? 1.f / ssum : 0.f;

    float acc = 0.f;
    for (int base = beg; base < end; base += 64) {
        int rem = end - base;
        if (rem > 64) rem = 64;
        int sv = 0;
        float av = 0.f;
        if (lane < rem) {
            sv = esrc[base + lane];
            av = __expf(leaky(el[sv] + erd) - m) * inv;
        }
        #pragma unroll 4
        for (int e = 0; e < rem; e++) {
            int s = __shfl(sv, e);
            float a = __shfl(av, e);
            acc += __half2float(feat[(size_t)s * 64 + lane]) * a;
        }
    }
    out[(size_t)wid * 64 + lane] = acc + bias[lane];
}

extern "C" void kernel_launch(void* const* d_in, const int* in_sizes, int n_in,
                              void* d_out, int out_size, void* d_ws, size_t ws_size,
                              hipStream_t stream) {
    const float* h   = (const float*)d_in[0];
    const int*   src = (const int*)d_in[1];
    const int*   dst = (const int*)d_in[2];
    const float* W1  = (const float*)d_in[3];
    const float* al1 = (const float*)d_in[4];
    const float* ar1 = (const float*)d_in[5];
    const float* b1  = (const float*)d_in[6];
    const float* W2  = (const float*)d_in[7];
    const float* al2 = (const float*)d_in[8];
    const float* ar2 = (const float*)d_in[9];
    const float* b2  = (const float*)d_in[10];
    const float* W3  = (const float*)d_in[11];
    const float* al3 = (const float*)d_in[12];
    const float* ar3 = (const float*)d_in[13];
    const float* b3  = (const float*)d_in[14];
    float* out = (float*)d_out;

    const int n = NNODES;
    __half* feat16 = (__half*)d_ws;                         // n*128 fp16
    float*  hbuf   = (float*)(feat16 + (size_t)n * 128);    // n*128 f32
    float*  el     = hbuf + (size_t)n * 128;                // n*4
    float*  er     = el + (size_t)n * 4;                    // n*4
    int*    cnt    = (int*)(er + (size_t)n * 4);            // n
    int*    offs   = cnt + n;                               // n+1
    int*    esrc   = offs + (n + 1);                        // NEDGES
    int*    bsum   = esrc + NEDGES;                         // nBlk
    int*    rank   = (int*)hbuf;                            // alias: dead before hbuf written

    const int gemmBlocks = (n + 63) / 64;
    const int nBlk = (n + 255) / 256;
    const int eBlk = (NEDGES + 255) / 256;
    const int waveBlk = (n + 3) / 4;

    // ---------- CSR build (graph shared by all 3 layers) ----------
    zero_k<<<nBlk, 256, 0, stream>>>(cnt, n);
    hist_k<<<eBlk, 256, 0, stream>>>(dst, cnt, rank);
    scan_blk_k<<<nBlk, 256, 0, stream>>>(cnt, offs, bsum, n);
    scan_top_k<<<1, 256, 0, stream>>>(bsum, nBlk);
    scan_add_k<<<nBlk, 256, 0, stream>>>(offs, bsum, n);
    scatter_k<<<eBlk, 256, 0, stream>>>(src, dst, rank, offs, esrc);

    // ---------- layer 1: 128 -> 4 heads x 32, relu ----------
    gemm_dots_k<128, 4><<<gemmBlocks, 256, 0, stream>>>(h, W1, al1, ar1, feat16, el, er, n);
    node_agg4_k<true><<<waveBlk, 256, 0, stream>>>(offs, esrc, el, er, feat16, b1, hbuf);

    // ---------- layer 2: 128 -> 4 heads x 32, relu ----------
    gemm_dots_k<128, 4><<<gemmBlocks, 256, 0, stream>>>(hbuf, W2, al2, ar2, feat16, el, er, n);
    node_agg4_k<true><<<waveBlk, 256, 0, stream>>>(offs, esrc, el, er, feat16, b2, hbuf);

    // ---------- layer 3: 128 -> 1 head x 64, no relu ----------
    gemm_dots_k<64, 1><<<gemmBlocks, 256, 0, stream>>>(hbuf, W3, al3, ar3, feat16, el, er, n);
    node_agg1_k<<<waveBlk, 256, 0, stream>>>(offs, esrc, el, er, feat16, b3, out);
}

// Round 6
// 285.037 us; speedup vs baseline: 13.3595x; 1.2504x over previous
//
#include <hip/hip_runtime.h>
#include <hip/hip_fp16.h>

#define NNODES 50000
#define NEDGES 800000

__device__ __forceinline__ float leaky(float x) { return x >= 0.f ? x : 0.2f * x; }

struct __align__(8) half4v { __half2 x, y; };

// ---- fused GEMM + attention dots, fp16 feature output ----------------------
// Yh[n x F] (fp16) = X[n x 128] @ W[128 x F]; el/er[n x H] = head dots (f32).
template<int F, int H>
__global__ __launch_bounds__(256) void gemm_dots_k(const float* __restrict__ X,
                                                   const float* __restrict__ W,
                                                   const float* __restrict__ al,
                                                   const float* __restrict__ ar,
                                                   __half* __restrict__ Yh,
                                                   float* __restrict__ el,
                                                   float* __restrict__ er, int n) {
    constexpr int K = 128;
    constexpr int KC = 64;
    constexpr int ROWS = 64;
    constexpr int CG = F / 8;
    constexpr int RR = ROWS / (256 / CG);
    __shared__ float Ws[KC * F];
    __shared__ float Xs[ROWS * KC];

    const int tid = threadIdx.x;
    const int cg = tid % CG, rg = tid / CG;
    const int c0a = cg * 4, c0b = F / 2 + cg * 4;
    const int rbase = rg * RR;
    const int r0 = blockIdx.x * ROWS;

    float acca[RR][4], accb[RR][4];
    #pragma unroll
    for (int r = 0; r < RR; r++)
        #pragma unroll
        for (int c = 0; c < 4; c++) { acca[r][c] = 0.f; accb[r][c] = 0.f; }

    for (int kc = 0; kc < K; kc += KC) {
        __syncthreads();
        {
            const float4* W4 = (const float4*)(W + (size_t)kc * F);
            float4* Ws4 = (float4*)Ws;
            #pragma unroll
            for (int i = tid; i < KC * F / 4; i += 256) Ws4[i] = W4[i];
        }
        {
            float4* Xs4 = (float4*)Xs;
            #pragma unroll
            for (int i = tid; i < ROWS * (KC / 4); i += 256) {
                int r = i / (KC / 4), q = i % (KC / 4);
                int row = r0 + r;
                Xs4[i] = (row < n) ? ((const float4*)X)[(size_t)row * (K / 4) + kc / 4 + q]
                                   : make_float4(0.f, 0.f, 0.f, 0.f);
            }
        }
        __syncthreads();
        #pragma unroll 4
        for (int k = 0; k < KC; k++) {
            float4 wa = *(const float4*)&Ws[k * F + c0a];
            float4 wb = *(const float4*)&Ws[k * F + c0b];
            #pragma unroll
            for (int r = 0; r < RR; r++) {
                float x = Xs[(rbase + r) * KC + k];
                acca[r][0] += x * wa.x; acca[r][1] += x * wa.y;
                acca[r][2] += x * wa.z; acca[r][3] += x * wa.w;
                accb[r][0] += x * wb.x; accb[r][1] += x * wb.y;
                accb[r][2] += x * wb.z; accb[r][3] += x * wb.w;
            }
        }
    }

    #pragma unroll
    for (int r = 0; r < RR; r++) {
        int row = r0 + rbase + r;
        if (row < n) {
            half4v ha, hb;
            ha.x = __halves2half2(__float2half_rn(acca[r][0]), __float2half_rn(acca[r][1]));
            ha.y = __halves2half2(__float2half_rn(acca[r][2]), __float2half_rn(acca[r][3]));
            hb.x = __halves2half2(__float2half_rn(accb[r][0]), __float2half_rn(accb[r][1]));
            hb.y = __halves2half2(__float2half_rn(accb[r][2]), __float2half_rn(accb[r][3]));
            *(half4v*)&Yh[(size_t)row * F + c0a] = ha;
            *(half4v*)&Yh[(size_t)row * F + c0b] = hb;
        }
    }

    float4 ala = *(const float4*)&al[c0a];
    float4 alb = *(const float4*)&al[c0b];
    float4 ara = *(const float4*)&ar[c0a];
    float4 arb = *(const float4*)&ar[c0b];
    #pragma unroll
    for (int r = 0; r < RR; r++) {
        float pla = acca[r][0]*ala.x + acca[r][1]*ala.y + acca[r][2]*ala.z + acca[r][3]*ala.w;
        float plb = accb[r][0]*alb.x + accb[r][1]*alb.y + accb[r][2]*alb.z + accb[r][3]*alb.w;
        float pra = acca[r][0]*ara.x + acca[r][1]*ara.y + acca[r][2]*ara.z + acca[r][3]*ara.w;
        float prb = accb[r][0]*arb.x + accb[r][1]*arb.y + accb[r][2]*arb.z + accb[r][3]*arb.w;
        if (H == 1) { pla += plb; pra += prb; }
        #pragma unroll
        for (int off = 1; off < 8; off <<= 1) {
            pla += __shfl_xor(pla, off);
            pra += __shfl_xor(pra, off);
            if (H > 1) { plb += __shfl_xor(plb, off); prb += __shfl_xor(prb, off); }
        }
        int row = r0 + rbase + r;
        if ((cg & 7) == 0 && row < n) {
            if (H == 1) {
                el[row] = pla; er[row] = pra;
            } else {
                int hd = cg / 8;
                el[row * H + hd] = pla;     er[row * H + hd] = pra;
                el[row * H + hd + 2] = plb; er[row * H + hd + 2] = prb;
            }
        }
    }
}

// ---------------- CSR build -------------------------------------------------
__global__ void zero_k(int* __restrict__ cnt, int n) {
    int i = blockIdx.x * blockDim.x + threadIdx.x;
    if (i < n) cnt[i] = 0;
}

__global__ void hist_k(const int* __restrict__ dst, int* __restrict__ cnt,
                       int* __restrict__ rank) {
    int e = blockIdx.x * blockDim.x + threadIdx.x;
    if (e < NEDGES) rank[e] = atomicAdd(&cnt[dst[e]], 1);
}

__global__ void scan_blk_k(const int* __restrict__ cnt, int* __restrict__ offs,
                           int* __restrict__ bsum, int n) {
    __shared__ int sm[256];
    int tid = threadIdx.x;
    int i = blockIdx.x * 256 + tid;
    int v = (i < n) ? cnt[i] : 0;
    sm[tid] = v;
    __syncthreads();
    for (int off = 1; off < 256; off <<= 1) {
        int t = (tid >= off) ? sm[tid - off] : 0;
        __syncthreads();
        sm[tid] += t;
        __syncthreads();
    }
    if (i < n) offs[i] = sm[tid] - v;
    if (tid == 255) bsum[blockIdx.x] = sm[255];
}

__global__ void scan_top_k(int* __restrict__ bsum, int nb) {
    __shared__ int sm[256];
    int tid = threadIdx.x;
    int v = (tid < nb) ? bsum[tid] : 0;
    sm[tid] = v;
    __syncthreads();
    for (int off = 1; off < 256; off <<= 1) {
        int t = (tid >= off) ? sm[tid - off] : 0;
        __syncthreads();
        sm[tid] += t;
        __syncthreads();
    }
    if (tid < nb) bsum[tid] = sm[tid] - v;
}

__global__ void scan_add_k(int* __restrict__ offs, const int* __restrict__ bsum, int n) {
    int i = blockIdx.x * 256 + threadIdx.x;
    if (i < n) offs[i] += bsum[blockIdx.x];
    if (i == 0) offs[n] = NEDGES;
}

__global__ void scatter_k(const int* __restrict__ src, const int* __restrict__ dst,
                          const int* __restrict__ rank, const int* __restrict__ offs,
                          int* __restrict__ esrc) {
    int e = blockIdx.x * blockDim.x + threadIdx.x;
    if (e < NEDGES) esrc[offs[dst[e]] + rank[e]] = src[e];
}

// ---------------- fused single-pass softmax+aggregate, H=4 D=32 ------------
// One wave per node. Per 16-edge chunk: lanes compute the 16x4 unnormalized
// p=exp(ev) once; inner loop does 2 edges/iter (lane halves), each lane
// gathering 4 halfs (8B). Normalize by the p-sum at the end.
template<bool RELU>
__global__ __launch_bounds__(256) void node_agg4_k(const int* __restrict__ offs,
                                                   const int* __restrict__ esrc,
                                                   const float* __restrict__ el,
                                                   const float* __restrict__ er,
                                                   const __half* __restrict__ feat,
                                                   const float* __restrict__ bias,
                                                   float* __restrict__ out) {
    int wid = (blockIdx.x * 256 + threadIdx.x) >> 6;
    int lane = threadIdx.x & 63;
    if (wid >= NNODES) return;
    int beg = offs[wid], end = offs[wid + 1];

    const int h  = lane & 3;     // head for p-compute (edge slot = lane>>2)
    const int l5 = lane >> 5;    // edge selector within pair
    const int cl = lane & 31;    // column group: cols 4cl..4cl+3
    const int hd = cl >> 3;      // head of column group
    float erh = er[wid * 4 + h];

    float acc0 = 0.f, acc1 = 0.f, acc2 = 0.f, acc3 = 0.f, dsum = 0.f;
    for (int base = beg; base < end; base += 16) {
        int rem = end - base;
        if (rem > 16) rem = 16;
        int sv = 0;
        if (lane < rem) sv = esrc[base + lane];
        int se = __shfl(sv, lane >> 2);
        float p = 0.f;
        if ((lane >> 2) < rem)
            p = __expf(leaky(el[se * 4 + h] + erh));
        dsum += p;
        #pragma unroll 4
        for (int e = 0; e < rem; e += 2) {
            int eidx = e + l5;                       // may be >= rem (odd rem): p=0, sv=0
            int s = __shfl(sv, eidx);
            float a = __shfl(p, eidx * 4 + hd);
            half4v hv = *(const half4v*)&feat[(size_t)s * 128 + 4 * cl];
            float2 f01 = __half22float2(hv.x);
            float2 f23 = __half22float2(hv.y);
            acc0 += f01.x * a; acc1 += f01.y * a;
            acc2 += f23.x * a; acc3 += f23.y * a;
        }
    }
    #pragma unroll
    for (int off = 4; off < 64; off <<= 1) dsum += __shfl_xor(dsum, off);
    acc0 += __shfl_xor(acc0, 32);
    acc1 += __shfl_xor(acc1, 32);
    acc2 += __shfl_xor(acc2, 32);
    acc3 += __shfl_xor(acc3, 32);
    float dh = __shfl(dsum, hd);                     // lane hd holds head hd's sum
    float inv = dh > 0.f ? 1.f / dh : 0.f;
    if (l5 == 0) {
        float4 b4 = *(const float4*)&bias[4 * cl];
        float v0 = acc0 * inv + b4.x, v1 = acc1 * inv + b4.y;
        float v2 = acc2 * inv + b4.z, v3 = acc3 * inv + b4.w;
        if (RELU) {
            v0 = fmaxf(v0, 0.f); v1 = fmaxf(v1, 0.f);
            v2 = fmaxf(v2, 0.f); v3 = fmaxf(v3, 0.f);
        }
        *(float4*)&out[(size_t)wid * 128 + 4 * cl] = make_float4(v0, v1, v2, v3);
    }
}

// ---------------- fused single-pass softmax+aggregate, H=1 D=64 ------------
__global__ __launch_bounds__(256) void node_agg1_k(const int* __restrict__ offs,
                                                   const int* __restrict__ esrc,
                                                   const float* __restrict__ el,
                                                   const float* __restrict__ er,
                                                   const __half* __restrict__ feat,
                                                   const float* __restrict__ bias,
                                                   float* __restrict__ out) {
    int wid = (blockIdx.x * 256 + threadIdx.x) >> 6;
    int lane = threadIdx.x & 63;
    if (wid >= NNODES) return;
    int beg = offs[wid], end = offs[wid + 1];

    const int l5 = lane >> 5;
    const int cl = lane & 31;    // column pair: cols 2cl, 2cl+1
    float erd = er[wid];

    float acc0 = 0.f, acc1 = 0.f, dsum = 0.f;
    for (int base = beg; base < end; base += 64) {
        int rem = end - base;
        if (rem > 64) rem = 64;
        int sv = 0;
        float p = 0.f;
        if (lane < rem) {
            sv = esrc[base + lane];
            p = __expf(leaky(el[sv] + erd));
        }
        dsum += p;
        #pragma unroll 4
        for (int e = 0; e < rem; e += 2) {
            int eidx = e + l5;
            int s = __shfl(sv, eidx);
            float a = __shfl(p, eidx);
            __half2 f2 = ((const __half2*)feat)[(size_t)s * 32 + cl];
            float2 ff = __half22float2(f2);
            acc0 += ff.x * a;
            acc1 += ff.y * a;
        }
    }
    #pragma unroll
    for (int off = 1; off < 64; off <<= 1) dsum += __shfl_xor(dsum, off);
    acc0 += __shfl_xor(acc0, 32);
    acc1 += __shfl_xor(acc1, 32);
    float inv = dsum > 0.f ? 1.f / dsum : 0.f;
    if (l5 == 0) {
        float2 b2 = *(const float2*)&bias[2 * cl];
        *(float2*)&out[(size_t)wid * 64 + 2 * cl] =
            make_float2(acc0 * inv + b2.x, acc1 * inv + b2.y);
    }
}

extern "C" void kernel_launch(void* const* d_in, const int* in_sizes, int n_in,
                              void* d_out, int out_size, void* d_ws, size_t ws_size,
                              hipStream_t stream) {
    const float* h   = (const float*)d_in[0];
    const int*   src = (const int*)d_in[1];
    const int*   dst = (const int*)d_in[2];
    const float* W1  = (const float*)d_in[3];
    const float* al1 = (const float*)d_in[4];
    const float* ar1 = (const float*)d_in[5];
    const float* b1  = (const float*)d_in[6];
    const float* W2  = (const float*)d_in[7];
    const float* al2 = (const float*)d_in[8];
    const float* ar2 = (const float*)d_in[9];
    const float* b2  = (const float*)d_in[10];
    const float* W3  = (const float*)d_in[11];
    const float* al3 = (const float*)d_in[12];
    const float* ar3 = (const float*)d_in[13];
    const float* b3  = (const float*)d_in[14];
    float* out = (float*)d_out;

    const int n = NNODES;
    __half* feat16 = (__half*)d_ws;                         // n*128 fp16
    float*  hbuf   = (float*)(feat16 + (size_t)n * 128);    // n*128 f32
    float*  el     = hbuf + (size_t)n * 128;                // n*4
    float*  er     = el + (size_t)n * 4;                    // n*4
    int*    cnt    = (int*)(er + (size_t)n * 4);            // n
    int*    offs   = cnt + n;                               // n+1
    int*    esrc   = offs + (n + 1);                        // NEDGES
    int*    bsum   = esrc + NEDGES;                         // nBlk
    int*    rank   = (int*)hbuf;                            // alias: dead before hbuf written

    const int gemmBlocks = (n + 63) / 64;
    const int nBlk = (n + 255) / 256;
    const int eBlk = (NEDGES + 255) / 256;
    const int waveBlk = (n + 3) / 4;

    // ---------- CSR build (graph shared by all 3 layers) ----------
    zero_k<<<nBlk, 256, 0, stream>>>(cnt, n);
    hist_k<<<eBlk, 256, 0, stream>>>(dst, cnt, rank);
    scan_blk_k<<<nBlk, 256, 0, stream>>>(cnt, offs, bsum, n);
    scan_top_k<<<1, 256, 0, stream>>>(bsum, nBlk);
    scan_add_k<<<nBlk, 256, 0, stream>>>(offs, bsum, n);
    scatter_k<<<eBlk, 256, 0, stream>>>(src, dst, rank, offs, esrc);

    // ---------- layer 1: 128 -> 4 heads x 32, relu ----------
    gemm_dots_k<128, 4><<<gemmBlocks, 256, 0, stream>>>(h, W1, al1, ar1, feat16, el, er, n);
    node_agg4_k<true><<<waveBlk, 256, 0, stream>>>(offs, esrc, el, er, feat16, b1, hbuf);

    // ---------- layer 2: 128 -> 4 heads x 32, relu ----------
    gemm_dots_k<128, 4><<<gemmBlocks, 256, 0, stream>>>(hbuf, W2, al2, ar2, feat16, el, er, n);
    node_agg4_k<true><<<waveBlk, 256, 0, stream>>>(offs, esrc, el, er, feat16, b2, hbuf);

    // ---------- layer 3: 128 -> 1 head x 64, no relu ----------
    gemm_dots_k<64, 1><<<gemmBlocks, 256, 0, stream>>>(hbuf, W3, al3, ar3, feat16, el, er, n);
    node_agg1_k<<<waveBlk, 256, 0, stream>>>(offs, esrc, el, er, feat16, b3, out);
}

// Round 7
// 243.950 us; speedup vs baseline: 15.6095x; 1.1684x over previous
//
#include <hip/hip_runtime.h>
#include <hip/hip_fp16.h>

#define NNODES 50000
#define NEDGES 800000

__device__ __forceinline__ float leaky(float x) { return x >= 0.f ? x : 0.2f * x; }

typedef _Float16 f16x8 __attribute__((ext_vector_type(8)));
typedef float f32x4 __attribute__((ext_vector_type(4)));

struct __align__(8)  half4v { __half2 h0, h1; };
struct __align__(16) half8v { __half2 h0, h1, h2, h3; };

// ---- MFMA GEMM + fused attention dots --------------------------------------
// Yh[n x F] (fp16) = X[n x 128] @ W[128 x F]  via v_mfma_f32_16x16x32_f16.
// el/er[n x H] = per-head dots with al/ar, from the f32 accumulators.
// Block: 64 rows, 256 threads (4 waves, 16 rows/wave). Whole K=128 staged.
template<int F, int H>
__global__ __launch_bounds__(256) void gemm_mfma_k(const float* __restrict__ X,
                                                   const float* __restrict__ W,
                                                   const float* __restrict__ al,
                                                   const float* __restrict__ ar,
                                                   __half* __restrict__ Yh,
                                                   float* __restrict__ el,
                                                   float* __restrict__ er, int n) {
    constexpr int K = 128;
    constexpr int ROWS = 64;
    constexpr int LDK = K + 8;          // halfs; 272B rows (16B-aligned, bank-spread)
    constexpr int NT = F / 16;          // N-tiles (8 for F=128, 4 for F=64)
    __shared__ __align__(16) __half Xs[ROWS * LDK];
    __shared__ __align__(16) __half Wt[F * LDK];   // transposed: Wt[ncol][k]

    const int tid = threadIdx.x;
    const int r0 = blockIdx.x * ROWS;

    // stage X block (f32 -> fp16, row-major)
    for (int i = tid; i < ROWS * (K / 4); i += 256) {
        int r = i >> 5, c4 = i & 31;
        int row = r0 + r;
        float4 v = (row < n) ? ((const float4*)X)[(size_t)row * (K / 4) + c4]
                             : make_float4(0.f, 0.f, 0.f, 0.f);
        __half* d = &Xs[r * LDK + c4 * 4];
        d[0] = __float2half_rn(v.x); d[1] = __float2half_rn(v.y);
        d[2] = __float2half_rn(v.z); d[3] = __float2half_rn(v.w);
    }
    // stage W transposed (f32 -> fp16): Wt[nn][k] = W[k][nn]
    for (int i = tid; i < K * (F / 4); i += 256) {
        int k = i / (F / 4), n4 = i % (F / 4);
        float4 v = ((const float4*)W)[i];
        int nn = n4 * 4;
        Wt[(nn + 0) * LDK + k] = __float2half_rn(v.x);
        Wt[(nn + 1) * LDK + k] = __float2half_rn(v.y);
        Wt[(nn + 2) * LDK + k] = __float2half_rn(v.z);
        Wt[(nn + 3) * LDK + k] = __float2half_rn(v.w);
    }
    __syncthreads();

    const int wv = tid >> 6, lane = tid & 63;
    const int cl = lane & 15, kg = lane >> 4;      // kg = k-group 0..3

    f32x4 acc[NT];
    #pragma unroll
    for (int t = 0; t < NT; t++) acc[t] = (f32x4){0.f, 0.f, 0.f, 0.f};

    #pragma unroll
    for (int ks = 0; ks < K / 32; ks++) {
        f16x8 a = *(const f16x8*)&Xs[(16 * wv + cl) * LDK + ks * 32 + kg * 8];
        #pragma unroll
        for (int t = 0; t < NT; t++) {
            f16x8 b = *(const f16x8*)&Wt[(16 * t + cl) * LDK + ks * 32 + kg * 8];
            acc[t] = __builtin_amdgcn_mfma_f32_16x16x32_f16(a, b, acc[t], 0, 0, 0);
        }
    }

    // store Yh: C layout col=lane&15, row=(lane>>4)*4+j  [HW-verified m89]
    #pragma unroll
    for (int t = 0; t < NT; t++)
        #pragma unroll
        for (int j = 0; j < 4; j++) {
            int row = r0 + 16 * wv + 4 * kg + j;
            if (row < n) Yh[(size_t)row * F + 16 * t + cl] = __float2half_rn(acc[t][j]);
        }

    // fused attention dots from f32 accumulators
    float alv[NT], arv[NT];
    #pragma unroll
    for (int t = 0; t < NT; t++) { alv[t] = al[16 * t + cl]; arv[t] = ar[16 * t + cl]; }

    if (H == 1) {
        float pl[4], pr[4];
        #pragma unroll
        for (int j = 0; j < 4; j++) {
            pl[j] = 0.f; pr[j] = 0.f;
            #pragma unroll
            for (int t = 0; t < NT; t++) { pl[j] += acc[t][j] * alv[t]; pr[j] += acc[t][j] * arv[t]; }
        }
        #pragma unroll
        for (int off = 1; off < 16; off <<= 1)
            #pragma unroll
            for (int j = 0; j < 4; j++) { pl[j] += __shfl_xor(pl[j], off); pr[j] += __shfl_xor(pr[j], off); }
        if (cl == 0)
            #pragma unroll
            for (int j = 0; j < 4; j++) {
                int row = r0 + 16 * wv + 4 * kg + j;
                if (row < n) { el[row] = pl[j]; er[row] = pr[j]; }
            }
    } else {
        float pl[4][4], pr[4][4];          // [head][j]
        #pragma unroll
        for (int hh = 0; hh < 4; hh++)
            #pragma unroll
            for (int j = 0; j < 4; j++) {
                pl[hh][j] = acc[2 * hh][j] * alv[2 * hh] + acc[2 * hh + 1][j] * alv[2 * hh + 1];
                pr[hh][j] = acc[2 * hh][j] * arv[2 * hh] + acc[2 * hh + 1][j] * arv[2 * hh + 1];
            }
        #pragma unroll
        for (int off = 1; off < 16; off <<= 1)
            #pragma unroll
            for (int hh = 0; hh < 4; hh++)
                #pragma unroll
                for (int j = 0; j < 4; j++) {
                    pl[hh][j] += __shfl_xor(pl[hh][j], off);
                    pr[hh][j] += __shfl_xor(pr[hh][j], off);
                }
        if (cl == 0)
            #pragma unroll
            for (int j = 0; j < 4; j++) {
                int row = r0 + 16 * wv + 4 * kg + j;
                if (row < n)
                    #pragma unroll
                    for (int hh = 0; hh < 4; hh++) {
                        el[row * 4 + hh] = pl[hh][j];
                        er[row * 4 + hh] = pr[hh][j];
                    }
            }
    }
}

// ---------------- CSR build -------------------------------------------------
__global__ void zero_k(int* __restrict__ cnt, int n) {
    int i = blockIdx.x * blockDim.x + threadIdx.x;
    if (i < n) cnt[i] = 0;
}

__global__ void hist_k(const int* __restrict__ dst, int* __restrict__ cnt,
                       int* __restrict__ rank) {
    int e = blockIdx.x * blockDim.x + threadIdx.x;
    if (e < NEDGES) rank[e] = atomicAdd(&cnt[dst[e]], 1);
}

__global__ void scan_blk_k(const int* __restrict__ cnt, int* __restrict__ offs,
                           int* __restrict__ bsum, int n) {
    __shared__ int sm[256];
    int tid = threadIdx.x;
    int i = blockIdx.x * 256 + tid;
    int v = (i < n) ? cnt[i] : 0;
    sm[tid] = v;
    __syncthreads();
    for (int off = 1; off < 256; off <<= 1) {
        int t = (tid >= off) ? sm[tid - off] : 0;
        __syncthreads();
        sm[tid] += t;
        __syncthreads();
    }
    if (i < n) offs[i] = sm[tid] - v;
    if (tid == 255) bsum[blockIdx.x] = sm[255];
}

__global__ void scan_top_k(int* __restrict__ bsum, int nb) {
    __shared__ int sm[256];
    int tid = threadIdx.x;
    int v = (tid < nb) ? bsum[tid] : 0;
    sm[tid] = v;
    __syncthreads();
    for (int off = 1; off < 256; off <<= 1) {
        int t = (tid >= off) ? sm[tid - off] : 0;
        __syncthreads();
        sm[tid] += t;
        __syncthreads();
    }
    if (tid < nb) bsum[tid] = sm[tid] - v;
}

__global__ void scan_add_k(int* __restrict__ offs, const int* __restrict__ bsum, int n) {
    int i = blockIdx.x * 256 + threadIdx.x;
    if (i < n) offs[i] += bsum[blockIdx.x];
    if (i == 0) offs[n] = NEDGES;
}

__global__ void scatter_k(const int* __restrict__ src, const int* __restrict__ dst,
                          const int* __restrict__ rank, const int* __restrict__ offs,
                          int* __restrict__ esrc) {
    int e = blockIdx.x * blockDim.x + threadIdx.x;
    if (e < NEDGES) esrc[offs[dst[e]] + rank[e]] = src[e];
}

// ---------------- fused single-pass softmax+aggregate, H=4 D=32 ------------
// One wave/node. 16-edge chunks: 64 lanes compute the 16x4 unnormalized
// p=exp(ev) once; inner loop runs 4 edges/iter (quarter-waves), each lane
// gathering 8 halfs (16B). Normalize by the p-sum at the end.
template<bool RELU>
__global__ __launch_bounds__(256) void node_agg4_k(const int* __restrict__ offs,
                                                   const int* __restrict__ esrc,
                                                   const float* __restrict__ el,
                                                   const float* __restrict__ er,
                                                   const __half* __restrict__ feat,
                                                   const float* __restrict__ bias,
                                                   float* __restrict__ out) {
    int wid = (blockIdx.x * 256 + threadIdx.x) >> 6;
    int lane = threadIdx.x & 63;
    if (wid >= NNODES) return;
    int beg = offs[wid], end = offs[wid + 1];

    const int h  = lane & 3;     // head for p-compute (edge slot = lane>>2)
    const int q  = lane >> 4;    // quarter: edge selector within 4-pack
    const int cl = lane & 15;    // col-group: cols 8cl..8cl+7
    const int hd = cl >> 2;      // head of col-group
    float erh = er[wid * 4 + h];

    float acc[8] = {0.f, 0.f, 0.f, 0.f, 0.f, 0.f, 0.f, 0.f};
    float dsum = 0.f;
    for (int base = beg; base < end; base += 16) {
        int rem = end - base;
        if (rem > 16) rem = 16;
        int sv = 0;
        if (lane < rem) sv = esrc[base + lane];
        int se = __shfl(sv, lane >> 2);
        float p = 0.f;
        if ((lane >> 2) < rem)
            p = __expf(leaky(el[se * 4 + h] + erh));
        dsum += p;
        #pragma unroll
        for (int e = 0; e < 16 && e < rem; e += 4) {
            int eidx = e + q;                        // <= 15 always
            int s = __shfl(sv, eidx);
            float a = __shfl(p, eidx * 4 + hd);      // 0 for eidx >= rem
            half8v hv = *(const half8v*)&feat[(size_t)s * 128 + 8 * cl];
            float2 f0 = __half22float2(hv.h0);
            float2 f1 = __half22float2(hv.h1);
            float2 f2 = __half22float2(hv.h2);
            float2 f3 = __half22float2(hv.h3);
            acc[0] += f0.x * a; acc[1] += f0.y * a;
            acc[2] += f1.x * a; acc[3] += f1.y * a;
            acc[4] += f2.x * a; acc[5] += f2.y * a;
            acc[6] += f3.x * a; acc[7] += f3.y * a;
        }
    }
    #pragma unroll
    for (int c = 0; c < 8; c++) {
        acc[c] += __shfl_xor(acc[c], 16);
        acc[c] += __shfl_xor(acc[c], 32);
    }
    #pragma unroll
    for (int off = 4; off < 64; off <<= 1) dsum += __shfl_xor(dsum, off);
    float dh = __shfl(dsum, hd);
    float inv = dh > 0.f ? 1.f / dh : 0.f;
    if (q == 0) {
        float4 ba = *(const float4*)&bias[8 * cl];
        float4 bb = *(const float4*)&bias[8 * cl + 4];
        float v0 = acc[0] * inv + ba.x, v1 = acc[1] * inv + ba.y;
        float v2 = acc[2] * inv + ba.z, v3 = acc[3] * inv + ba.w;
        float v4 = acc[4] * inv + bb.x, v5 = acc[5] * inv + bb.y;
        float v6 = acc[6] * inv + bb.z, v7 = acc[7] * inv + bb.w;
        if (RELU) {
            v0 = fmaxf(v0, 0.f); v1 = fmaxf(v1, 0.f); v2 = fmaxf(v2, 0.f); v3 = fmaxf(v3, 0.f);
            v4 = fmaxf(v4, 0.f); v5 = fmaxf(v5, 0.f); v6 = fmaxf(v6, 0.f); v7 = fmaxf(v7, 0.f);
        }
        *(float4*)&out[(size_t)wid * 128 + 8 * cl]     = make_float4(v0, v1, v2, v3);
        *(float4*)&out[(size_t)wid * 128 + 8 * cl + 4] = make_float4(v4, v5, v6, v7);
    }
}

// ---------------- fused single-pass softmax+aggregate, H=1 D=64 ------------
__global__ __launch_bounds__(256) void node_agg1_k(const int* __restrict__ offs,
                                                   const int* __restrict__ esrc,
                                                   const float* __restrict__ el,
                                                   const float* __restrict__ er,
                                                   const __half* __restrict__ feat,
                                                   const float* __restrict__ bias,
                                                   float* __restrict__ out) {
    int wid = (blockIdx.x * 256 + threadIdx.x) >> 6;
    int lane = threadIdx.x & 63;
    if (wid >= NNODES) return;
    int beg = offs[wid], end = offs[wid + 1];

    const int q  = lane >> 4;
    const int cl = lane & 15;    // cols 4cl..4cl+3
    float erd = er[wid];

    float acc[4] = {0.f, 0.f, 0.f, 0.f};
    float dsum = 0.f;
    for (int base = beg; base < end; base += 64) {
        int rem = end - base;
        if (rem > 64) rem = 64;
        int sv = 0;
        float p = 0.f;
        if (lane < rem) {
            sv = esrc[base + lane];
            p = __expf(leaky(el[sv] + erd));
        }
        dsum += p;
        #pragma unroll 4
        for (int e = 0; e < rem; e += 4) {
            int eidx = e + q;                        // <= 63 always
            int s = __shfl(sv, eidx);
            float a = __shfl(p, eidx);               // 0 for eidx >= rem
            half4v hv = *(const half4v*)&feat[(size_t)s * 64 + 4 * cl];
            float2 f0 = __half22float2(hv.h0);
            float2 f1 = __half22float2(hv.h1);
            acc[0] += f0.x * a; acc[1] += f0.y * a;
            acc[2] += f1.x * a; acc[3] += f1.y * a;
        }
    }
    #pragma unroll
    for (int c = 0; c < 4; c++) {
        acc[c] += __shfl_xor(acc[c], 16);
        acc[c] += __shfl_xor(acc[c], 32);
    }
    #pragma unroll
    for (int off = 1; off < 64; off <<= 1) dsum += __shfl_xor(dsum, off);
    float inv = dsum > 0.f ? 1.f / dsum : 0.f;
    if (q == 0) {
        float4 b4 = *(const float4*)&bias[4 * cl];
        *(float4*)&out[(size_t)wid * 64 + 4 * cl] =
            make_float4(acc[0] * inv + b4.x, acc[1] * inv + b4.y,
                        acc[2] * inv + b4.z, acc[3] * inv + b4.w);
    }
}

extern "C" void kernel_launch(void* const* d_in, const int* in_sizes, int n_in,
                              void* d_out, int out_size, void* d_ws, size_t ws_size,
                              hipStream_t stream) {
    const float* h   = (const float*)d_in[0];
    const int*   src = (const int*)d_in[1];
    const int*   dst = (const int*)d_in[2];
    const float* W1  = (const float*)d_in[3];
    const float* al1 = (const float*)d_in[4];
    const float* ar1 = (const float*)d_in[5];
    const float* b1  = (const float*)d_in[6];
    const float* W2  = (const float*)d_in[7];
    const float* al2 = (const float*)d_in[8];
    const float* ar2 = (const float*)d_in[9];
    const float* b2  = (const float*)d_in[10];
    const float* W3  = (const float*)d_in[11];
    const float* al3 = (const float*)d_in[12];
    const float* ar3 = (const float*)d_in[13];
    const float* b3  = (const float*)d_in[14];
    float* out = (float*)d_out;

    const int n = NNODES;
    __half* feat16 = (__half*)d_ws;                         // n*128 fp16
    float*  hbuf   = (float*)(feat16 + (size_t)n * 128);    // n*128 f32
    float*  el     = hbuf + (size_t)n * 128;                // n*4
    float*  er     = el + (size_t)n * 4;                    // n*4
    int*    cnt    = (int*)(er + (size_t)n * 4);            // n
    int*    offs   = cnt + n;                               // n+1
    int*    esrc   = offs + (n + 1);                        // NEDGES
    int*    bsum   = esrc + NEDGES;                         // nBlk
    int*    rank   = (int*)hbuf;                            // alias: dead before hbuf written

    const int gemmBlocks = (n + 63) / 64;
    const int nBlk = (n + 255) / 256;
    const int eBlk = (NEDGES + 255) / 256;
    const int waveBlk = (n + 3) / 4;

    // ---------- CSR build (graph shared by all 3 layers) ----------
    zero_k<<<nBlk, 256, 0, stream>>>(cnt, n);
    hist_k<<<eBlk, 256, 0, stream>>>(dst, cnt, rank);
    scan_blk_k<<<nBlk, 256, 0, stream>>>(cnt, offs, bsum, n);
    scan_top_k<<<1, 256, 0, stream>>>(bsum, nBlk);
    scan_add_k<<<nBlk, 256, 0, stream>>>(offs, bsum, n);
    scatter_k<<<eBlk, 256, 0, stream>>>(src, dst, rank, offs, esrc);

    // ---------- layer 1: 128 -> 4 heads x 32, relu ----------
    gemm_mfma_k<128, 4><<<gemmBlocks, 256, 0, stream>>>(h, W1, al1, ar1, feat16, el, er, n);
    node_agg4_k<true><<<waveBlk, 256, 0, stream>>>(offs, esrc, el, er, feat16, b1, hbuf);

    // ---------- layer 2: 128 -> 4 heads x 32, relu ----------
    gemm_mfma_k<128, 4><<<gemmBlocks, 256, 0, stream>>>(hbuf, W2, al2, ar2, feat16, el, er, n);
    node_agg4_k<true><<<waveBlk, 256, 0, stream>>>(offs, esrc, el, er, feat16, b2, hbuf);

    // ---------- layer 3: 128 -> 1 head x 64, no relu ----------
    gemm_mfma_k<64, 1><<<gemmBlocks, 256, 0, stream>>>(hbuf, W3, al3, ar3, feat16, el, er, n);
    node_agg1_k<<<waveBlk, 256, 0, stream>>>(offs, esrc, el, er, feat16, b3, out);
}

// Round 8
// 233.314 us; speedup vs baseline: 16.3211x; 1.0456x over previous
//
#include <hip/hip_runtime.h>
#include <hip/hip_fp16.h>

#define NNODES 50000
#define NEDGES 800000

__device__ __forceinline__ float leaky(float x) { return x >= 0.f ? x : 0.2f * x; }

typedef _Float16 f16x8 __attribute__((ext_vector_type(8)));
typedef float f32x4 __attribute__((ext_vector_type(4)));

struct __align__(8)  half4v { __half2 h0, h1; };
struct __align__(16) half8v { __half2 h0, h1, h2, h3; };

// ---- MFMA GEMM + fused attention dots --------------------------------------
// Yh[n x F] (fp16) = X[n x 128] @ W[128 x F]  via v_mfma_f32_16x16x32_f16.
// el/er[n x H] = per-head dots with al/ar, from the f32 accumulators.
// Block: 64 rows, 256 threads (4 waves, 16 rows/wave). Whole K=128 staged.
template<int F, int H, bool FP16IN>
__global__ __launch_bounds__(256) void gemm_mfma_k(const void* __restrict__ Xv,
                                                   const float* __restrict__ W,
                                                   const float* __restrict__ al,
                                                   const float* __restrict__ ar,
                                                   __half* __restrict__ Yh,
                                                   float* __restrict__ el,
                                                   float* __restrict__ er, int n) {
    constexpr int K = 128;
    constexpr int ROWS = 64;
    constexpr int LDK = K + 8;          // halfs; 272B rows (16B-aligned, bank-spread)
    constexpr int NT = F / 16;          // N-tiles (8 for F=128, 4 for F=64)
    __shared__ __align__(16) __half Xs[ROWS * LDK];
    __shared__ __align__(16) __half Wt[F * LDK];   // transposed: Wt[ncol][k]

    const int tid = threadIdx.x;
    const int r0 = blockIdx.x * ROWS;

    // stage X block (row-major fp16 in LDS)
    if constexpr (FP16IN) {
        const __half* X = (const __half*)Xv;
        for (int i = tid; i < ROWS * (K / 8); i += 256) {
            int r = i >> 4, c8 = i & 15;
            int row = r0 + r;
            half8v v;
            __half2 z = __halves2half2(__float2half_rn(0.f), __float2half_rn(0.f));
            v.h0 = z; v.h1 = z; v.h2 = z; v.h3 = z;
            if (row < n) v = ((const half8v*)X)[(size_t)row * (K / 8) + c8];
            *(half8v*)&Xs[r * LDK + c8 * 8] = v;
        }
    } else {
        const float* X = (const float*)Xv;
        for (int i = tid; i < ROWS * (K / 4); i += 256) {
            int r = i >> 5, c4 = i & 31;
            int row = r0 + r;
            float4 v = (row < n) ? ((const float4*)X)[(size_t)row * (K / 4) + c4]
                                 : make_float4(0.f, 0.f, 0.f, 0.f);
            __half* d = &Xs[r * LDK + c4 * 4];
            d[0] = __float2half_rn(v.x); d[1] = __float2half_rn(v.y);
            d[2] = __float2half_rn(v.z); d[3] = __float2half_rn(v.w);
        }
    }
    // stage W transposed (f32 -> fp16): Wt[nn][k] = W[k][nn]
    for (int i = tid; i < K * (F / 4); i += 256) {
        int k = i / (F / 4), n4 = i % (F / 4);
        float4 v = ((const float4*)W)[i];
        int nn = n4 * 4;
        Wt[(nn + 0) * LDK + k] = __float2half_rn(v.x);
        Wt[(nn + 1) * LDK + k] = __float2half_rn(v.y);
        Wt[(nn + 2) * LDK + k] = __float2half_rn(v.z);
        Wt[(nn + 3) * LDK + k] = __float2half_rn(v.w);
    }
    __syncthreads();

    const int wv = tid >> 6, lane = tid & 63;
    const int cl = lane & 15, kg = lane >> 4;      // kg = k-group 0..3

    f32x4 acc[NT];
    #pragma unroll
    for (int t = 0; t < NT; t++) acc[t] = (f32x4){0.f, 0.f, 0.f, 0.f};

    #pragma unroll
    for (int ks = 0; ks < K / 32; ks++) {
        f16x8 a = *(const f16x8*)&Xs[(16 * wv + cl) * LDK + ks * 32 + kg * 8];
        #pragma unroll
        for (int t = 0; t < NT; t++) {
            f16x8 b = *(const f16x8*)&Wt[(16 * t + cl) * LDK + ks * 32 + kg * 8];
            acc[t] = __builtin_amdgcn_mfma_f32_16x16x32_f16(a, b, acc[t], 0, 0, 0);
        }
    }

    // store Yh: C layout col=lane&15, row=(lane>>4)*4+j  [HW-verified m89]
    #pragma unroll
    for (int t = 0; t < NT; t++)
        #pragma unroll
        for (int j = 0; j < 4; j++) {
            int row = r0 + 16 * wv + 4 * kg + j;
            if (row < n) Yh[(size_t)row * F + 16 * t + cl] = __float2half_rn(acc[t][j]);
        }

    // fused attention dots from f32 accumulators
    float alv[NT], arv[NT];
    #pragma unroll
    for (int t = 0; t < NT; t++) { alv[t] = al[16 * t + cl]; arv[t] = ar[16 * t + cl]; }

    if (H == 1) {
        float pl[4], pr[4];
        #pragma unroll
        for (int j = 0; j < 4; j++) {
            pl[j] = 0.f; pr[j] = 0.f;
            #pragma unroll
            for (int t = 0; t < NT; t++) { pl[j] += acc[t][j] * alv[t]; pr[j] += acc[t][j] * arv[t]; }
        }
        #pragma unroll
        for (int off = 1; off < 16; off <<= 1)
            #pragma unroll
            for (int j = 0; j < 4; j++) { pl[j] += __shfl_xor(pl[j], off); pr[j] += __shfl_xor(pr[j], off); }
        if (cl == 0)
            #pragma unroll
            for (int j = 0; j < 4; j++) {
                int row = r0 + 16 * wv + 4 * kg + j;
                if (row < n) { el[row] = pl[j]; er[row] = pr[j]; }
            }
    } else {
        float pl[4][4], pr[4][4];          // [head][j]
        #pragma unroll
        for (int hh = 0; hh < 4; hh++)
            #pragma unroll
            for (int j = 0; j < 4; j++) {
                pl[hh][j] = acc[2 * hh][j] * alv[2 * hh] + acc[2 * hh + 1][j] * alv[2 * hh + 1];
                pr[hh][j] = acc[2 * hh][j] * arv[2 * hh] + acc[2 * hh + 1][j] * arv[2 * hh + 1];
            }
        #pragma unroll
        for (int off = 1; off < 16; off <<= 1)
            #pragma unroll
            for (int hh = 0; hh < 4; hh++)
                #pragma unroll
                for (int j = 0; j < 4; j++) {
                    pl[hh][j] += __shfl_xor(pl[hh][j], off);
                    pr[hh][j] += __shfl_xor(pr[hh][j], off);
                }
        if (cl == 0)
            #pragma unroll
            for (int j = 0; j < 4; j++) {
                int row = r0 + 16 * wv + 4 * kg + j;
                if (row < n)
                    #pragma unroll
                    for (int hh = 0; hh < 4; hh++) {
                        el[row * 4 + hh] = pl[hh][j];
                        er[row * 4 + hh] = pr[hh][j];
                    }
            }
    }
}

// ---------------- CSR build -------------------------------------------------
__global__ void zero_k(int* __restrict__ cnt, int n) {
    int i = blockIdx.x * blockDim.x + threadIdx.x;
    if (i < n) cnt[i] = 0;
}

__global__ void hist_k(const int* __restrict__ dst, int* __restrict__ cnt,
                       int* __restrict__ rank) {
    int e = blockIdx.x * blockDim.x + threadIdx.x;
    if (e < NEDGES) rank[e] = atomicAdd(&cnt[dst[e]], 1);
}

__global__ void scan_blk_k(const int* __restrict__ cnt, int* __restrict__ offs,
                           int* __restrict__ bsum, int n) {
    __shared__ int sm[256];
    int tid = threadIdx.x;
    int i = blockIdx.x * 256 + tid;
    int v = (i < n) ? cnt[i] : 0;
    sm[tid] = v;
    __syncthreads();
    for (int off = 1; off < 256; off <<= 1) {
        int t = (tid >= off) ? sm[tid - off] : 0;
        __syncthreads();
        sm[tid] += t;
        __syncthreads();
    }
    if (i < n) offs[i] = sm[tid] - v;
    if (tid == 255) bsum[blockIdx.x] = sm[255];
}

__global__ void scan_top_k(int* __restrict__ bsum, int nb) {
    __shared__ int sm[256];
    int tid = threadIdx.x;
    int v = (tid < nb) ? bsum[tid] : 0;
    sm[tid] = v;
    __syncthreads();
    for (int off = 1; off < 256; off <<= 1) {
        int t = (tid >= off) ? sm[tid - off] : 0;
        __syncthreads();
        sm[tid] += t;
        __syncthreads();
    }
    if (tid < nb) bsum[tid] = sm[tid] - v;
}

__global__ void scan_add_k(int* __restrict__ offs, const int* __restrict__ bsum, int n) {
    int i = blockIdx.x * 256 + threadIdx.x;
    if (i < n) offs[i] += bsum[blockIdx.x];
    if (i == 0) offs[n] = NEDGES;
}

__global__ void scatter_k(const int* __restrict__ src, const int* __restrict__ dst,
                          const int* __restrict__ rank, const int* __restrict__ offs,
                          int* __restrict__ esrc) {
    int e = blockIdx.x * blockDim.x + threadIdx.x;
    if (e < NEDGES) esrc[offs[dst[e]] + rank[e]] = src[e];
}

// ---------------- fused single-pass softmax+aggregate, H=4 D=32 ------------
// Persistent waves: grid-stride over nodes, one wave per node per iteration.
// 16-edge chunks: 64 lanes compute 16x4 unnormalized p=exp(ev) once; inner
// loop runs 4 edges/iter (quarter-waves), each lane gathering 16B. Output
// fp16 with relu + bias (feeds next layer's fp16 GEMM directly).
__global__ __launch_bounds__(256) void node_agg4_k(const int* __restrict__ offs,
                                                   const int* __restrict__ esrc,
                                                   const float* __restrict__ el,
                                                   const float* __restrict__ er,
                                                   const __half* __restrict__ feat,
                                                   const float* __restrict__ bias,
                                                   __half* __restrict__ out) {
    const int lane = threadIdx.x & 63;
    const int gw0 = (blockIdx.x * 256 + threadIdx.x) >> 6;
    const int NW = (gridDim.x * 256) >> 6;

    const int h  = lane & 3;     // head for p-compute (edge slot = lane>>2)
    const int q  = lane >> 4;    // quarter: edge selector within 4-pack
    const int cl = lane & 15;    // col-group: cols 8cl..8cl+7
    const int hd = cl >> 2;      // head of col-group

    float4 ba, bb;
    ba = *(const float4*)&bias[8 * cl];
    bb = *(const float4*)&bias[8 * cl + 4];

    for (int wid = gw0; wid < NNODES; wid += NW) {
        int beg = offs[wid], end = offs[wid + 1];
        float erh = er[wid * 4 + h];

        float acc[8] = {0.f, 0.f, 0.f, 0.f, 0.f, 0.f, 0.f, 0.f};
        float dsum = 0.f;
        for (int base = beg; base < end; base += 16) {
            int rem = end - base;
            if (rem > 16) rem = 16;
            int sv = 0;
            if (lane < rem) sv = esrc[base + lane];
            int se = __shfl(sv, lane >> 2);
            float p = 0.f;
            if ((lane >> 2) < rem)
                p = __expf(leaky(el[se * 4 + h] + erh));
            dsum += p;
            #pragma unroll
            for (int e = 0; e < 16 && e < rem; e += 4) {
                int eidx = e + q;                        // <= 15 always
                int s = __shfl(sv, eidx);
                float a = __shfl(p, eidx * 4 + hd);      // 0 for eidx >= rem
                half8v hv = *(const half8v*)&feat[(size_t)s * 128 + 8 * cl];
                float2 f0 = __half22float2(hv.h0);
                float2 f1 = __half22float2(hv.h1);
                float2 f2 = __half22float2(hv.h2);
                float2 f3 = __half22float2(hv.h3);
                acc[0] += f0.x * a; acc[1] += f0.y * a;
                acc[2] += f1.x * a; acc[3] += f1.y * a;
                acc[4] += f2.x * a; acc[5] += f2.y * a;
                acc[6] += f3.x * a; acc[7] += f3.y * a;
            }
        }
        #pragma unroll
        for (int c = 0; c < 8; c++) {
            acc[c] += __shfl_xor(acc[c], 16);
            acc[c] += __shfl_xor(acc[c], 32);
        }
        #pragma unroll
        for (int off = 4; off < 64; off <<= 1) dsum += __shfl_xor(dsum, off);
        float dh = __shfl(dsum, hd);
        float inv = dh > 0.f ? 1.f / dh : 0.f;
        if (q == 0) {
            float v0 = fmaxf(acc[0] * inv + ba.x, 0.f), v1 = fmaxf(acc[1] * inv + ba.y, 0.f);
            float v2 = fmaxf(acc[2] * inv + ba.z, 0.f), v3 = fmaxf(acc[3] * inv + ba.w, 0.f);
            float v4 = fmaxf(acc[4] * inv + bb.x, 0.f), v5 = fmaxf(acc[5] * inv + bb.y, 0.f);
            float v6 = fmaxf(acc[6] * inv + bb.z, 0.f), v7 = fmaxf(acc[7] * inv + bb.w, 0.f);
            half8v hv;
            hv.h0 = __halves2half2(__float2half_rn(v0), __float2half_rn(v1));
            hv.h1 = __halves2half2(__float2half_rn(v2), __float2half_rn(v3));
            hv.h2 = __halves2half2(__float2half_rn(v4), __float2half_rn(v5));
            hv.h3 = __halves2half2(__float2half_rn(v6), __float2half_rn(v7));
            *(half8v*)&out[(size_t)wid * 128 + 8 * cl] = hv;
        }
    }
}

// ---------------- fused single-pass softmax+aggregate, H=1 D=64 ------------
__global__ __launch_bounds__(256) void node_agg1_k(const int* __restrict__ offs,
                                                   const int* __restrict__ esrc,
                                                   const float* __restrict__ el,
                                                   const float* __restrict__ er,
                                                   const __half* __restrict__ feat,
                                                   const float* __restrict__ bias,
                                                   float* __restrict__ out) {
    const int lane = threadIdx.x & 63;
    const int gw0 = (blockIdx.x * 256 + threadIdx.x) >> 6;
    const int NW = (gridDim.x * 256) >> 6;

    const int q  = lane >> 4;
    const int cl = lane & 15;    // cols 4cl..4cl+3
    float4 b4 = *(const float4*)&bias[4 * cl];

    for (int wid = gw0; wid < NNODES; wid += NW) {
        int beg = offs[wid], end = offs[wid + 1];
        float erd = er[wid];

        float acc[4] = {0.f, 0.f, 0.f, 0.f};
        float dsum = 0.f;
        for (int base = beg; base < end; base += 64) {
            int rem = end - base;
            if (rem > 64) rem = 64;
            int sv = 0;
            float p = 0.f;
            if (lane < rem) {
                sv = esrc[base + lane];
                p = __expf(leaky(el[sv] + erd));
            }
            dsum += p;
            #pragma unroll 4
            for (int e = 0; e < rem; e += 4) {
                int eidx = e + q;                        // <= 63 always
                int s = __shfl(sv, eidx);
                float a = __shfl(p, eidx);               // 0 for eidx >= rem
                half4v hv = *(const half4v*)&feat[(size_t)s * 64 + 4 * cl];
                float2 f0 = __half22float2(hv.h0);
                float2 f1 = __half22float2(hv.h1);
                acc[0] += f0.x * a; acc[1] += f0.y * a;
                acc[2] += f1.x * a; acc[3] += f1.y * a;
            }
        }
        #pragma unroll
        for (int c = 0; c < 4; c++) {
            acc[c] += __shfl_xor(acc[c], 16);
            acc[c] += __shfl_xor(acc[c], 32);
        }
        #pragma unroll
        for (int off = 1; off < 64; off <<= 1) dsum += __shfl_xor(dsum, off);
        float inv = dsum > 0.f ? 1.f / dsum : 0.f;
        if (q == 0) {
            *(float4*)&out[(size_t)wid * 64 + 4 * cl] =
                make_float4(acc[0] * inv + b4.x, acc[1] * inv + b4.y,
                            acc[2] * inv + b4.z, acc[3] * inv + b4.w);
        }
    }
}

extern "C" void kernel_launch(void* const* d_in, const int* in_sizes, int n_in,
                              void* d_out, int out_size, void* d_ws, size_t ws_size,
                              hipStream_t stream) {
    const float* h   = (const float*)d_in[0];
    const int*   src = (const int*)d_in[1];
    const int*   dst = (const int*)d_in[2];
    const float* W1  = (const float*)d_in[3];
    const float* al1 = (const float*)d_in[4];
    const float* ar1 = (const float*)d_in[5];
    const float* b1  = (const float*)d_in[6];
    const float* W2  = (const float*)d_in[7];
    const float* al2 = (const float*)d_in[8];
    const float* ar2 = (const float*)d_in[9];
    const float* b2  = (const float*)d_in[10];
    const float* W3  = (const float*)d_in[11];
    const float* al3 = (const float*)d_in[12];
    const float* ar3 = (const float*)d_in[13];
    const float* b3  = (const float*)d_in[14];
    float* out = (float*)d_out;

    const int n = NNODES;
    __half* feat16 = (__half*)d_ws;                         // n*128 fp16
    __half* hbuf16 = feat16 + (size_t)n * 128;              // n*128 fp16
    float*  el     = (float*)(hbuf16 + (size_t)n * 128);    // n*4
    float*  er     = el + (size_t)n * 4;                    // n*4
    int*    cnt    = (int*)(er + (size_t)n * 4);            // n
    int*    offs   = cnt + n;                               // n+1
    int*    esrc   = offs + (n + 1);                        // NEDGES
    int*    bsum   = esrc + NEDGES;                         // nBlk
    int*    rank   = (int*)feat16;                          // alias: dead before feat16 written

    const int gemmBlocks = (n + 63) / 64;
    const int nBlk = (n + 255) / 256;
    const int eBlk = (NEDGES + 255) / 256;
    const int aggBlk = 2048;                                // 256 CU x 8 blocks, persistent

    // ---------- CSR build (graph shared by all 3 layers) ----------
    zero_k<<<nBlk, 256, 0, stream>>>(cnt, n);
    hist_k<<<eBlk, 256, 0, stream>>>(dst, cnt, rank);
    scan_blk_k<<<nBlk, 256, 0, stream>>>(cnt, offs, bsum, n);
    scan_top_k<<<1, 256, 0, stream>>>(bsum, nBlk);
    scan_add_k<<<nBlk, 256, 0, stream>>>(offs, bsum, n);
    scatter_k<<<eBlk, 256, 0, stream>>>(src, dst, rank, offs, esrc);

    // ---------- layer 1: 128 -> 4 heads x 32, relu ----------
    gemm_mfma_k<128, 4, false><<<gemmBlocks, 256, 0, stream>>>(h, W1, al1, ar1, feat16, el, er, n);
    node_agg4_k<<<aggBlk, 256, 0, stream>>>(offs, esrc, el, er, feat16, b1, hbuf16);

    // ---------- layer 2: 128 -> 4 heads x 32, relu ----------
    gemm_mfma_k<128, 4, true><<<gemmBlocks, 256, 0, stream>>>(hbuf16, W2, al2, ar2, feat16, el, er, n);
    node_agg4_k<<<aggBlk, 256, 0, stream>>>(offs, esrc, el, er, feat16, b2, hbuf16);

    // ---------- layer 3: 128 -> 1 head x 64, no relu ----------
    gemm_mfma_k<64, 1, true><<<gemmBlocks, 256, 0, stream>>>(hbuf16, W3, al3, ar3, feat16, el, er, n);
    node_agg1_k<<<aggBlk, 256, 0, stream>>>(offs, esrc, el, er, feat16, b3, out);
}

// Round 10
// 222.089 us; speedup vs baseline: 17.1460x; 1.0505x over previous
//
#include <hip/hip_runtime.h>
#include <hip/hip_fp16.h>

#define NNODES 50000
#define NEDGES 800000
#define HISTB 256   // extra blocks fused into gemm1 for the histogram

__device__ __forceinline__ float leaky(float x) { return x >= 0.f ? x : 0.2f * x; }

typedef _Float16 f16x8 __attribute__((ext_vector_type(8)));
typedef float f32x4 __attribute__((ext_vector_type(4)));

struct __align__(8)  half4v { __half2 h0, h1; };
struct __align__(16) half8v { __half2 h0, h1, h2, h3; };

// ---- MFMA GEMM + fused attention dots (+ optional fused edge histogram) ----
// Yh[n x F] (fp16) = X[n x 128] @ W[128 x F]  via v_mfma_f32_16x16x32_f16.
// el/er[n x H] from the f32 accumulators. Blocks >= nGemm run the histogram.
template<int F, int H, bool FP16IN, bool DO_HIST>
__global__ __launch_bounds__(256) void gemm_mfma_k(const void* __restrict__ Xv,
                                                   const float* __restrict__ W,
                                                   const float* __restrict__ al,
                                                   const float* __restrict__ ar,
                                                   __half* __restrict__ Yh,
                                                   float* __restrict__ el,
                                                   float* __restrict__ er, int n,
                                                   int nGemm,
                                                   const int* __restrict__ dst,
                                                   int* __restrict__ cnt,
                                                   int* __restrict__ rank) {
    constexpr int K = 128;
    constexpr int ROWS = 64;
    constexpr int LDK = K + 8;
    constexpr int NT = F / 16;

    if (DO_HIST && blockIdx.x >= nGemm) {
        int b = blockIdx.x - nGemm;
        for (int e = b * 256 + threadIdx.x; e < NEDGES; e += HISTB * 256)
            rank[e] = atomicAdd(&cnt[dst[e]], 1);
        return;
    }

    __shared__ __align__(16) __half Xs[ROWS * LDK];
    __shared__ __align__(16) __half Wt[F * LDK];

    const int tid = threadIdx.x;
    const int r0 = blockIdx.x * ROWS;

    if constexpr (FP16IN) {
        const __half* X = (const __half*)Xv;
        for (int i = tid; i < ROWS * (K / 8); i += 256) {
            int r = i >> 4, c8 = i & 15;
            int row = r0 + r;
            half8v v;
            __half2 z = __halves2half2(__float2half_rn(0.f), __float2half_rn(0.f));
            v.h0 = z; v.h1 = z; v.h2 = z; v.h3 = z;
            if (row < n) v = ((const half8v*)X)[(size_t)row * (K / 8) + c8];
            *(half8v*)&Xs[r * LDK + c8 * 8] = v;
        }
    } else {
        const float* X = (const float*)Xv;
        for (int i = tid; i < ROWS * (K / 4); i += 256) {
            int r = i >> 5, c4 = i & 31;
            int row = r0 + r;
            float4 v = (row < n) ? ((const float4*)X)[(size_t)row * (K / 4) + c4]
                                 : make_float4(0.f, 0.f, 0.f, 0.f);
            __half* d = &Xs[r * LDK + c4 * 4];
            d[0] = __float2half_rn(v.x); d[1] = __float2half_rn(v.y);
            d[2] = __float2half_rn(v.z); d[3] = __float2half_rn(v.w);
        }
    }
    for (int i = tid; i < K * (F / 4); i += 256) {
        int k = i / (F / 4), n4 = i % (F / 4);
        float4 v = ((const float4*)W)[i];
        int nn = n4 * 4;
        Wt[(nn + 0) * LDK + k] = __float2half_rn(v.x);
        Wt[(nn + 1) * LDK + k] = __float2half_rn(v.y);
        Wt[(nn + 2) * LDK + k] = __float2half_rn(v.z);
        Wt[(nn + 3) * LDK + k] = __float2half_rn(v.w);
    }
    __syncthreads();

    const int wv = tid >> 6, lane = tid & 63;
    const int cl = lane & 15, kg = lane >> 4;

    f32x4 acc[NT];
    #pragma unroll
    for (int t = 0; t < NT; t++) acc[t] = (f32x4){0.f, 0.f, 0.f, 0.f};

    #pragma unroll
    for (int ks = 0; ks < K / 32; ks++) {
        f16x8 a = *(const f16x8*)&Xs[(16 * wv + cl) * LDK + ks * 32 + kg * 8];
        #pragma unroll
        for (int t = 0; t < NT; t++) {
            f16x8 b = *(const f16x8*)&Wt[(16 * t + cl) * LDK + ks * 32 + kg * 8];
            acc[t] = __builtin_amdgcn_mfma_f32_16x16x32_f16(a, b, acc[t], 0, 0, 0);
        }
    }

    #pragma unroll
    for (int t = 0; t < NT; t++)
        #pragma unroll
        for (int j = 0; j < 4; j++) {
            int row = r0 + 16 * wv + 4 * kg + j;
            if (row < n) Yh[(size_t)row * F + 16 * t + cl] = __float2half_rn(acc[t][j]);
        }

    float alv[NT], arv[NT];
    #pragma unroll
    for (int t = 0; t < NT; t++) { alv[t] = al[16 * t + cl]; arv[t] = ar[16 * t + cl]; }

    if (H == 1) {
        float pl[4], pr[4];
        #pragma unroll
        for (int j = 0; j < 4; j++) {
            pl[j] = 0.f; pr[j] = 0.f;
            #pragma unroll
            for (int t = 0; t < NT; t++) { pl[j] += acc[t][j] * alv[t]; pr[j] += acc[t][j] * arv[t]; }
        }
        #pragma unroll
        for (int off = 1; off < 16; off <<= 1)
            #pragma unroll
            for (int j = 0; j < 4; j++) { pl[j] += __shfl_xor(pl[j], off); pr[j] += __shfl_xor(pr[j], off); }
        if (cl == 0)
            #pragma unroll
            for (int j = 0; j < 4; j++) {
                int row = r0 + 16 * wv + 4 * kg + j;
                if (row < n) { el[row] = pl[j]; er[row] = pr[j]; }
            }
    } else {
        float pl[4][4], pr[4][4];
        #pragma unroll
        for (int hh = 0; hh < 4; hh++)
            #pragma unroll
            for (int j = 0; j < 4; j++) {
                pl[hh][j] = acc[2 * hh][j] * alv[2 * hh] + acc[2 * hh + 1][j] * alv[2 * hh + 1];
                pr[hh][j] = acc[2 * hh][j] * arv[2 * hh] + acc[2 * hh + 1][j] * arv[2 * hh + 1];
            }
        #pragma unroll
        for (int off = 1; off < 16; off <<= 1)
            #pragma unroll
            for (int hh = 0; hh < 4; hh++)
                #pragma unroll
                for (int j = 0; j < 4; j++) {
                    pl[hh][j] += __shfl_xor(pl[hh][j], off);
                    pr[hh][j] += __shfl_xor(pr[hh][j], off);
                }
        if (cl == 0)
            #pragma unroll
            for (int j = 0; j < 4; j++) {
                int row = r0 + 16 * wv + 4 * kg + j;
                if (row < n)
                    #pragma unroll
                    for (int hh = 0; hh < 4; hh++) {
                        el[row * 4 + hh] = pl[hh][j];
                        er[row * 4 + hh] = pr[hh][j];
                    }
            }
    }
}

// ---------------- CSR scan kernels ------------------------------------------
__global__ void scan_blk_k(const int* __restrict__ cnt, int* __restrict__ offs,
                           int* __restrict__ bsum, int n) {
    __shared__ int sm[256];
    int tid = threadIdx.x;
    int i = blockIdx.x * 256 + tid;
    int v = (i < n) ? cnt[i] : 0;
    sm[tid] = v;
    __syncthreads();
    for (int off = 1; off < 256; off <<= 1) {
        int t = (tid >= off) ? sm[tid - off] : 0;
        __syncthreads();
        sm[tid] += t;
        __syncthreads();
    }
    if (i < n) offs[i] = sm[tid] - v;
    if (tid == 255) bsum[blockIdx.x] = sm[255];
}

// each block redundantly scans the block sums in LDS, adds its exclusive prefix
__global__ void scan_addtop_k(int* __restrict__ offs, const int* __restrict__ bsum,
                              int n, int nb) {
    __shared__ int sm[256];
    int tid = threadIdx.x;
    int v = (tid < nb) ? bsum[tid] : 0;
    sm[tid] = v;
    __syncthreads();
    for (int off = 1; off < 256; off <<= 1) {
        int t = (tid >= off) ? sm[tid - off] : 0;
        __syncthreads();
        sm[tid] += t;
        __syncthreads();
    }
    int prefix = (blockIdx.x > 0) ? sm[blockIdx.x - 1] : 0;
    int i = blockIdx.x * 256 + tid;
    if (i < n) offs[i] += prefix;
    if (i == 0) offs[n] = NEDGES;
}

__global__ void scatter_k(const int* __restrict__ src, const int* __restrict__ dst,
                          const int* __restrict__ rank, const int* __restrict__ offs,
                          int* __restrict__ esrc) {
    int e = blockIdx.x * blockDim.x + threadIdx.x;
    if (e < NEDGES) esrc[offs[dst[e]] + rank[e]] = src[e];
}

// ---------------- fused single-pass softmax+aggregate, H=4 D=32 ------------
__global__ __launch_bounds__(256) void node_agg4_k(const int* __restrict__ offs,
                                                   const int* __restrict__ esrc,
                                                   const float* __restrict__ el,
                                                   const float* __restrict__ er,
                                                   const __half* __restrict__ feat,
                                                   const float* __restrict__ bias,
                                                   __half* __restrict__ out) {
    const int lane = threadIdx.x & 63;
    const int gw0 = (blockIdx.x * 256 + threadIdx.x) >> 6;
    const int NW = (gridDim.x * 256) >> 6;

    const int h  = lane & 3;
    const int q  = lane >> 4;
    const int cl = lane & 15;
    const int hd = cl >> 2;

    float4 ba = *(const float4*)&bias[8 * cl];
    float4 bb = *(const float4*)&bias[8 * cl + 4];

    for (int wid = gw0; wid < NNODES; wid += NW) {
        int beg = offs[wid], end = offs[wid + 1];
        float erh = er[wid * 4 + h];

        float acc[8] = {0.f, 0.f, 0.f, 0.f, 0.f, 0.f, 0.f, 0.f};
        float dsum = 0.f;
        for (int base = beg; base < end; base += 16) {
            int rem = end - base;
            if (rem > 16) rem = 16;
            int sv = 0;
            if (lane < rem) sv = esrc[base + lane];
            int se = __shfl(sv, lane >> 2);
            float p = 0.f;
            if ((lane >> 2) < rem)
                p = __expf(leaky(el[se * 4 + h] + erh));
            dsum += p;
            #pragma unroll
            for (int e = 0; e < 16 && e < rem; e += 4) {
                int eidx = e + q;
                int s = __shfl(sv, eidx);
                float a = __shfl(p, eidx * 4 + hd);
                half8v hv = *(const half8v*)&feat[(size_t)s * 128 + 8 * cl];
                float2 f0 = __half22float2(hv.h0);
                float2 f1 = __half22float2(hv.h1);
                float2 f2 = __half22float2(hv.h2);
                float2 f3 = __half22float2(hv.h3);
                acc[0] += f0.x * a; acc[1] += f0.y * a;
                acc[2] += f1.x * a; acc[3] += f1.y * a;
                acc[4] += f2.x * a; acc[5] += f2.y * a;
                acc[6] += f3.x * a; acc[7] += f3.y * a;
            }
        }
        #pragma unroll
        for (int c = 0; c < 8; c++) {
            acc[c] += __shfl_xor(acc[c], 16);
            acc[c] += __shfl_xor(acc[c], 32);
        }
        #pragma unroll
        for (int off = 4; off < 64; off <<= 1) dsum += __shfl_xor(dsum, off);
        float dh = __shfl(dsum, hd);
        float inv = dh > 0.f ? 1.f / dh : 0.f;
        if (q == 0) {
            float v0 = fmaxf(acc[0] * inv + ba.x, 0.f), v1 = fmaxf(acc[1] * inv + ba.y, 0.f);
            float v2 = fmaxf(acc[2] * inv + ba.z, 0.f), v3 = fmaxf(acc[3] * inv + ba.w, 0.f);
            float v4 = fmaxf(acc[4] * inv + bb.x, 0.f), v5 = fmaxf(acc[5] * inv + bb.y, 0.f);
            float v6 = fmaxf(acc[6] * inv + bb.z, 0.f), v7 = fmaxf(acc[7] * inv + bb.w, 0.f);
            half8v hv;
            hv.h0 = __halves2half2(__float2half_rn(v0), __float2half_rn(v1));
            hv.h1 = __halves2half2(__float2half_rn(v2), __float2half_rn(v3));
            hv.h2 = __halves2half2(__float2half_rn(v4), __float2half_rn(v5));
            hv.h3 = __halves2half2(__float2half_rn(v6), __float2half_rn(v7));
            *(half8v*)&out[(size_t)wid * 128 + 8 * cl] = hv;
        }
    }
}

// ---------------- fused single-pass softmax+aggregate, H=1 D=64 ------------
__global__ __launch_bounds__(256) void node_agg1_k(const int* __restrict__ offs,
                                                   const int* __restrict__ esrc,
                                                   const float* __restrict__ el,
                                                   const float* __restrict__ er,
                                                   const __half* __restrict__ feat,
                                                   const float* __restrict__ bias,
                                                   float* __restrict__ out) {
    const int lane = threadIdx.x & 63;
    const int gw0 = (blockIdx.x * 256 + threadIdx.x) >> 6;
    const int NW = (gridDim.x * 256) >> 6;

    const int q  = lane >> 4;
    const int cl = lane & 15;
    float4 b4 = *(const float4*)&bias[4 * cl];

    for (int wid = gw0; wid < NNODES; wid += NW) {
        int beg = offs[wid], end = offs[wid + 1];
        float erd = er[wid];

        float acc[4] = {0.f, 0.f, 0.f, 0.f};
        float dsum = 0.f;
        for (int base = beg; base < end; base += 64) {
            int rem = end - base;
            if (rem > 64) rem = 64;
            int sv = 0;
            float p = 0.f;
            if (lane < rem) {
                sv = esrc[base + lane];
                p = __expf(leaky(el[sv] + erd));
            }
            dsum += p;
            #pragma unroll 4
            for (int e = 0; e < rem; e += 4) {
                int eidx = e + q;
                int s = __shfl(sv, eidx);
                float a = __shfl(p, eidx);
                half4v hv = *(const half4v*)&feat[(size_t)s * 64 + 4 * cl];
                float2 f0 = __half22float2(hv.h0);
                float2 f1 = __half22float2(hv.h1);
                acc[0] += f0.x * a; acc[1] += f0.y * a;
                acc[2] += f1.x * a; acc[3] += f1.y * a;
            }
        }
        #pragma unroll
        for (int c = 0; c < 4; c++) {
            acc[c] += __shfl_xor(acc[c], 16);
            acc[c] += __shfl_xor(acc[c], 32);
        }
        #pragma unroll
        for (int off = 1; off < 64; off <<= 1) dsum += __shfl_xor(dsum, off);
        float inv = dsum > 0.f ? 1.f / dsum : 0.f;
        if (q == 0) {
            *(float4*)&out[(size_t)wid * 64 + 4 * cl] =
                make_float4(acc[0] * inv + b4.x, acc[1] * inv + b4.y,
                            acc[2] * inv + b4.z, acc[3] * inv + b4.w);
        }
    }
}

extern "C" void kernel_launch(void* const* d_in, const int* in_sizes, int n_in,
                              void* d_out, int out_size, void* d_ws, size_t ws_size,
                              hipStream_t stream) {
    const float* h   = (const float*)d_in[0];
    const int*   src = (const int*)d_in[1];
    const int*   dst = (const int*)d_in[2];
    const float* W1  = (const float*)d_in[3];
    const float* al1 = (const float*)d_in[4];
    const float* ar1 = (const float*)d_in[5];
    const float* b1  = (const float*)d_in[6];
    const float* W2  = (const float*)d_in[7];
    const float* al2 = (const float*)d_in[8];
    const float* ar2 = (const float*)d_in[9];
    const float* b2  = (const float*)d_in[10];
    const float* W3  = (const float*)d_in[11];
    const float* al3 = (const float*)d_in[12];
    const float* ar3 = (const float*)d_in[13];
    const float* b3  = (const float*)d_in[14];
    float* out = (float*)d_out;

    const int n = NNODES;
    __half* feat16 = (__half*)d_ws;                         // n*128 fp16
    __half* hbuf16 = feat16 + (size_t)n * 128;              // n*128 fp16
    float*  el     = (float*)(hbuf16 + (size_t)n * 128);    // n*4
    float*  er     = el + (size_t)n * 4;                    // n*4
    int*    cnt    = (int*)(er + (size_t)n * 4);            // n
    int*    offs   = cnt + n;                               // n+1
    int*    esrc   = offs + (n + 1);                        // NEDGES
    int*    bsum   = esrc + NEDGES;                         // nBlk
    int*    rank   = bsum + 256;                            // NEDGES (own region: gemm1 runs concurrently with hist)

    const int gemmBlocks = (n + 63) / 64;                   // 782
    const int nBlk = (n + 255) / 256;                       // 196
    const int eBlk = (NEDGES + 255) / 256;
    const int aggBlk = 2048;

    // ---------- zero counters (capture-legal async memset) ----------
    hipMemsetAsync(cnt, 0, (size_t)n * sizeof(int), stream);

    // ---------- layer-1 GEMM with fused edge histogram ----------
    gemm_mfma_k<128, 4, false, true><<<gemmBlocks + HISTB, 256, 0, stream>>>(
        h, W1, al1, ar1, feat16, el, er, n, gemmBlocks, dst, cnt, rank);

    // ---------- CSR scan + scatter ----------
    scan_blk_k<<<nBlk, 256, 0, stream>>>(cnt, offs, bsum, n);
    scan_addtop_k<<<nBlk, 256, 0, stream>>>(offs, bsum, n, nBlk);
    scatter_k<<<eBlk, 256, 0, stream>>>(src, dst, rank, offs, esrc);

    // ---------- layer 1 aggregate ----------
    node_agg4_k<<<aggBlk, 256, 0, stream>>>(offs, esrc, el, er, feat16, b1, hbuf16);

    // ---------- layer 2: 128 -> 4 heads x 32, relu ----------
    gemm_mfma_k<128, 4, true, false><<<gemmBlocks, 256, 0, stream>>>(
        hbuf16, W2, al2, ar2, feat16, el, er, n, gemmBlocks, nullptr, nullptr, nullptr);
    node_agg4_k<<<aggBlk, 256, 0, stream>>>(offs, esrc, el, er, feat16, b2, hbuf16);

    // ---------- layer 3: 128 -> 1 head x 64, no relu ----------
    gemm_mfma_k<64, 1, true, false><<<gemmBlocks, 256, 0, stream>>>(
        hbuf16, W3, al3, ar3, feat16, el, er, n, gemmBlocks, nullptr, nullptr, nullptr);
    node_agg1_k<<<aggBlk, 256, 0, stream>>>(offs, esrc, el, er, feat16, b3, out);
}

// Round 11
// 221.094 us; speedup vs baseline: 17.2232x; 1.0045x over previous
//
#include <hip/hip_runtime.h>
#include <hip/hip_fp16.h>

#define NNODES 50000
#define NEDGES 800000
#define HISTB 256   // extra blocks fused into gemm1 for the histogram

__device__ __forceinline__ float leaky(float x) { return x >= 0.f ? x : 0.2f * x; }

typedef _Float16 f16x8 __attribute__((ext_vector_type(8)));
typedef float f32x4 __attribute__((ext_vector_type(4)));

struct __align__(8)  half4v { __half2 h0, h1; };
struct __align__(16) half8v { __half2 h0, h1, h2, h3; };

// ---- W transpose/convert: Wt[col][k] fp16 for all three layers -------------
__global__ __launch_bounds__(256) void wtrans_k(const float* __restrict__ W1,
                                                const float* __restrict__ W2,
                                                const float* __restrict__ W3,
                                                __half* __restrict__ Wt) {
    int i = blockIdx.x * 256 + threadIdx.x;
    if (i < 16384) {                       // W1: [128][128]
        int k = i >> 7, c = i & 127;
        Wt[c * 128 + k] = __float2half_rn(W1[i]);
    } else if (i < 32768) {                // W2: [128][128]
        int e = i - 16384, k = e >> 7, c = e & 127;
        Wt[16384 + c * 128 + k] = __float2half_rn(W2[e]);
    } else if (i < 40960) {                // W3: [128][64]
        int e = i - 32768, k = e >> 6, c = e & 63;
        Wt[32768 + c * 128 + k] = __float2half_rn(W3[e]);
    }
}

// ---- LDS-free MFMA GEMM + fused attention dots (+ optional histogram) ------
// Yh[n x F] (fp16) = X[n x 128] @ W[128 x F] via v_mfma_f32_16x16x32_f16.
// A-fragments from global X (k-contiguous 16B), B-fragments from global Wt
// (pre-transposed fp16, L1/L2-resident). No LDS, no barriers.
template<int F, int H, bool FP16IN, bool DO_HIST>
__global__ __launch_bounds__(256) void gemm_mfma_k(const void* __restrict__ Xv,
                                                   const __half* __restrict__ Wt,
                                                   const float* __restrict__ al,
                                                   const float* __restrict__ ar,
                                                   __half* __restrict__ Yh,
                                                   float* __restrict__ el,
                                                   float* __restrict__ er, int n,
                                                   int nGemm,
                                                   const int* __restrict__ dst,
                                                   int* __restrict__ cnt,
                                                   int* __restrict__ rank) {
    constexpr int K = 128;
    constexpr int NT = F / 16;

    if (DO_HIST && blockIdx.x >= nGemm) {
        int b = blockIdx.x - nGemm;
        for (int e = b * 256 + threadIdx.x; e < NEDGES; e += HISTB * 256)
            rank[e] = atomicAdd(&cnt[dst[e]], 1);
        return;
    }

    const int tid = threadIdx.x;
    const int wv = tid >> 6, lane = tid & 63;
    const int cl = lane & 15, kg = lane >> 4;
    const int r0 = blockIdx.x * 64;
    const int rowA = r0 + 16 * wv + cl;
    const int rA = rowA < n ? rowA : n - 1;     // clamped load row (stores guarded)

    f32x4 acc[NT];
    #pragma unroll
    for (int t = 0; t < NT; t++) acc[t] = (f32x4){0.f, 0.f, 0.f, 0.f};

    #pragma unroll
    for (int ks = 0; ks < K / 32; ks++) {
        f16x8 a;
        if constexpr (FP16IN) {
            a = *(const f16x8*)((const __half*)Xv + (size_t)rA * K + ks * 32 + kg * 8);
        } else {
            const float* Xp = (const float*)Xv + (size_t)rA * K + ks * 32 + kg * 8;
            float4 x0 = *(const float4*)Xp;
            float4 x1 = *(const float4*)(Xp + 4);
            a[0] = (_Float16)x0.x; a[1] = (_Float16)x0.y;
            a[2] = (_Float16)x0.z; a[3] = (_Float16)x0.w;
            a[4] = (_Float16)x1.x; a[5] = (_Float16)x1.y;
            a[6] = (_Float16)x1.z; a[7] = (_Float16)x1.w;
        }
        #pragma unroll
        for (int t = 0; t < NT; t++) {
            f16x8 b = *(const f16x8*)(Wt + (size_t)(16 * t + cl) * K + ks * 32 + kg * 8);
            acc[t] = __builtin_amdgcn_mfma_f32_16x16x32_f16(a, b, acc[t], 0, 0, 0);
        }
    }

    // store Yh: C layout col=lane&15, row=(lane>>4)*4+j  [HW-verified m89]
    #pragma unroll
    for (int t = 0; t < NT; t++)
        #pragma unroll
        for (int j = 0; j < 4; j++) {
            int row = r0 + 16 * wv + 4 * kg + j;
            if (row < n) Yh[(size_t)row * F + 16 * t + cl] = __float2half_rn(acc[t][j]);
        }

    // fused attention dots from f32 accumulators
    float alv[NT], arv[NT];
    #pragma unroll
    for (int t = 0; t < NT; t++) { alv[t] = al[16 * t + cl]; arv[t] = ar[16 * t + cl]; }

    if (H == 1) {
        float pl[4], pr[4];
        #pragma unroll
        for (int j = 0; j < 4; j++) {
            pl[j] = 0.f; pr[j] = 0.f;
            #pragma unroll
            for (int t = 0; t < NT; t++) { pl[j] += acc[t][j] * alv[t]; pr[j] += acc[t][j] * arv[t]; }
        }
        #pragma unroll
        for (int off = 1; off < 16; off <<= 1)
            #pragma unroll
            for (int j = 0; j < 4; j++) { pl[j] += __shfl_xor(pl[j], off); pr[j] += __shfl_xor(pr[j], off); }
        if (cl == 0)
            #pragma unroll
            for (int j = 0; j < 4; j++) {
                int row = r0 + 16 * wv + 4 * kg + j;
                if (row < n) { el[row] = pl[j]; er[row] = pr[j]; }
            }
    } else {
        float pl[4][4], pr[4][4];          // [head][j]
        #pragma unroll
        for (int hh = 0; hh < 4; hh++)
            #pragma unroll
            for (int j = 0; j < 4; j++) {
                pl[hh][j] = acc[2 * hh][j] * alv[2 * hh] + acc[2 * hh + 1][j] * alv[2 * hh + 1];
                pr[hh][j] = acc[2 * hh][j] * arv[2 * hh] + acc[2 * hh + 1][j] * arv[2 * hh + 1];
            }
        #pragma unroll
        for (int off = 1; off < 16; off <<= 1)
            #pragma unroll
            for (int hh = 0; hh < 4; hh++)
                #pragma unroll
                for (int j = 0; j < 4; j++) {
                    pl[hh][j] += __shfl_xor(pl[hh][j], off);
                    pr[hh][j] += __shfl_xor(pr[hh][j], off);
                }
        if (cl == 0)
            #pragma unroll
            for (int j = 0; j < 4; j++) {
                int row = r0 + 16 * wv + 4 * kg + j;
                if (row < n)
                    #pragma unroll
                    for (int hh = 0; hh < 4; hh++) {
                        el[row * 4 + hh] = pl[hh][j];
                        er[row * 4 + hh] = pr[hh][j];
                    }
            }
    }
}

// ---------------- CSR scan kernels ------------------------------------------
__global__ void scan_blk_k(const int* __restrict__ cnt, int* __restrict__ offs,
                           int* __restrict__ bsum, int n) {
    __shared__ int sm[256];
    int tid = threadIdx.x;
    int i = blockIdx.x * 256 + tid;
    int v = (i < n) ? cnt[i] : 0;
    sm[tid] = v;
    __syncthreads();
    for (int off = 1; off < 256; off <<= 1) {
        int t = (tid >= off) ? sm[tid - off] : 0;
        __syncthreads();
        sm[tid] += t;
        __syncthreads();
    }
    if (i < n) offs[i] = sm[tid] - v;
    if (tid == 255) bsum[blockIdx.x] = sm[255];
}

__global__ void scan_addtop_k(int* __restrict__ offs, const int* __restrict__ bsum,
                              int n, int nb) {
    __shared__ int sm[256];
    int tid = threadIdx.x;
    int v = (tid < nb) ? bsum[tid] : 0;
    sm[tid] = v;
    __syncthreads();
    for (int off = 1; off < 256; off <<= 1) {
        int t = (tid >= off) ? sm[tid - off] : 0;
        __syncthreads();
        sm[tid] += t;
        __syncthreads();
    }
    int prefix = (blockIdx.x > 0) ? sm[blockIdx.x - 1] : 0;
    int i = blockIdx.x * 256 + tid;
    if (i < n) offs[i] += prefix;
    if (i == 0) offs[n] = NEDGES;
}

__global__ void scatter_k(const int* __restrict__ src, const int* __restrict__ dst,
                          const int* __restrict__ rank, const int* __restrict__ offs,
                          int* __restrict__ esrc) {
    int e = blockIdx.x * blockDim.x + threadIdx.x;
    if (e < NEDGES) esrc[offs[dst[e]] + rank[e]] = src[e];
}

// ---------------- fused single-pass softmax+aggregate, H=4 D=32 ------------
__global__ __launch_bounds__(256) void node_agg4_k(const int* __restrict__ offs,
                                                   const int* __restrict__ esrc,
                                                   const float* __restrict__ el,
                                                   const float* __restrict__ er,
                                                   const __half* __restrict__ feat,
                                                   const float* __restrict__ bias,
                                                   __half* __restrict__ out) {
    const int lane = threadIdx.x & 63;
    const int gw0 = (blockIdx.x * 256 + threadIdx.x) >> 6;
    const int NW = (gridDim.x * 256) >> 6;

    const int h  = lane & 3;
    const int q  = lane >> 4;
    const int cl = lane & 15;
    const int hd = cl >> 2;

    float4 ba = *(const float4*)&bias[8 * cl];
    float4 bb = *(const float4*)&bias[8 * cl + 4];

    for (int wid = gw0; wid < NNODES; wid += NW) {
        int beg = offs[wid], end = offs[wid + 1];
        float erh = er[wid * 4 + h];

        float acc[8] = {0.f, 0.f, 0.f, 0.f, 0.f, 0.f, 0.f, 0.f};
        float dsum = 0.f;
        for (int base = beg; base < end; base += 16) {
            int rem = end - base;
            if (rem > 16) rem = 16;
            int sv = 0;
            if (lane < rem) sv = esrc[base + lane];
            int se = __shfl(sv, lane >> 2);
            float p = 0.f;
            if ((lane >> 2) < rem)
                p = __expf(leaky(el[se * 4 + h] + erh));
            dsum += p;
            #pragma unroll
            for (int e = 0; e < 16 && e < rem; e += 4) {
                int eidx = e + q;
                int s = __shfl(sv, eidx);
                float a = __shfl(p, eidx * 4 + hd);
                half8v hv = *(const half8v*)&feat[(size_t)s * 128 + 8 * cl];
                float2 f0 = __half22float2(hv.h0);
                float2 f1 = __half22float2(hv.h1);
                float2 f2 = __half22float2(hv.h2);
                float2 f3 = __half22float2(hv.h3);
                acc[0] += f0.x * a; acc[1] += f0.y * a;
                acc[2] += f1.x * a; acc[3] += f1.y * a;
                acc[4] += f2.x * a; acc[5] += f2.y * a;
                acc[6] += f3.x * a; acc[7] += f3.y * a;
            }
        }
        #pragma unroll
        for (int c = 0; c < 8; c++) {
            acc[c] += __shfl_xor(acc[c], 16);
            acc[c] += __shfl_xor(acc[c], 32);
        }
        #pragma unroll
        for (int off = 4; off < 64; off <<= 1) dsum += __shfl_xor(dsum, off);
        float dh = __shfl(dsum, hd);
        float inv = dh > 0.f ? 1.f / dh : 0.f;
        if (q == 0) {
            float v0 = fmaxf(acc[0] * inv + ba.x, 0.f), v1 = fmaxf(acc[1] * inv + ba.y, 0.f);
            float v2 = fmaxf(acc[2] * inv + ba.z, 0.f), v3 = fmaxf(acc[3] * inv + ba.w, 0.f);
            float v4 = fmaxf(acc[4] * inv + bb.x, 0.f), v5 = fmaxf(acc[5] * inv + bb.y, 0.f);
            float v6 = fmaxf(acc[6] * inv + bb.z, 0.f), v7 = fmaxf(acc[7] * inv + bb.w, 0.f);
            half8v hv;
            hv.h0 = __halves2half2(__float2half_rn(v0), __float2half_rn(v1));
            hv.h1 = __halves2half2(__float2half_rn(v2), __float2half_rn(v3));
            hv.h2 = __halves2half2(__float2half_rn(v4), __float2half_rn(v5));
            hv.h3 = __halves2half2(__float2half_rn(v6), __float2half_rn(v7));
            *(half8v*)&out[(size_t)wid * 128 + 8 * cl] = hv;
        }
    }
}

// ---------------- fused single-pass softmax+aggregate, H=1 D=64 ------------
__global__ __launch_bounds__(256) void node_agg1_k(const int* __restrict__ offs,
                                                   const int* __restrict__ esrc,
                                                   const float* __restrict__ el,
                                                   const float* __restrict__ er,
                                                   const __half* __restrict__ feat,
                                                   const float* __restrict__ bias,
                                                   float* __restrict__ out) {
    const int lane = threadIdx.x & 63;
    const int gw0 = (blockIdx.x * 256 + threadIdx.x) >> 6;
    const int NW = (gridDim.x * 256) >> 6;

    const int q  = lane >> 4;
    const int cl = lane & 15;
    float4 b4 = *(const float4*)&bias[4 * cl];

    for (int wid = gw0; wid < NNODES; wid += NW) {
        int beg = offs[wid], end = offs[wid + 1];
        float erd = er[wid];

        float acc[4] = {0.f, 0.f, 0.f, 0.f};
        float dsum = 0.f;
        for (int base = beg; base < end; base += 64) {
            int rem = end - base;
            if (rem > 64) rem = 64;
            int sv = 0;
            float p = 0.f;
            if (lane < rem) {
                sv = esrc[base + lane];
                p = __expf(leaky(el[sv] + erd));
            }
            dsum += p;
            #pragma unroll 4
            for (int e = 0; e < rem; e += 4) {
                int eidx = e + q;
                int s = __shfl(sv, eidx);
                float a = __shfl(p, eidx);
                half4v hv = *(const half4v*)&feat[(size_t)s * 64 + 4 * cl];
                float2 f0 = __half22float2(hv.h0);
                float2 f1 = __half22float2(hv.h1);
                acc[0] += f0.x * a; acc[1] += f0.y * a;
                acc[2] += f1.x * a; acc[3] += f1.y * a;
            }
        }
        #pragma unroll
        for (int c = 0; c < 4; c++) {
            acc[c] += __shfl_xor(acc[c], 16);
            acc[c] += __shfl_xor(acc[c], 32);
        }
        #pragma unroll
        for (int off = 1; off < 64; off <<= 1) dsum += __shfl_xor(dsum, off);
        float inv = dsum > 0.f ? 1.f / dsum : 0.f;
        if (q == 0) {
            *(float4*)&out[(size_t)wid * 64 + 4 * cl] =
                make_float4(acc[0] * inv + b4.x, acc[1] * inv + b4.y,
                            acc[2] * inv + b4.z, acc[3] * inv + b4.w);
        }
    }
}

extern "C" void kernel_launch(void* const* d_in, const int* in_sizes, int n_in,
                              void* d_out, int out_size, void* d_ws, size_t ws_size,
                              hipStream_t stream) {
    const float* h   = (const float*)d_in[0];
    const int*   src = (const int*)d_in[1];
    const int*   dst = (const int*)d_in[2];
    const float* W1  = (const float*)d_in[3];
    const float* al1 = (const float*)d_in[4];
    const float* ar1 = (const float*)d_in[5];
    const float* b1  = (const float*)d_in[6];
    const float* W2  = (const float*)d_in[7];
    const float* al2 = (const float*)d_in[8];
    const float* ar2 = (const float*)d_in[9];
    const float* b2  = (const float*)d_in[10];
    const float* W3  = (const float*)d_in[11];
    const float* al3 = (const float*)d_in[12];
    const float* ar3 = (const float*)d_in[13];
    const float* b3  = (const float*)d_in[14];
    float* out = (float*)d_out;

    const int n = NNODES;
    __half* feat16 = (__half*)d_ws;                         // n*128 fp16
    __half* hbuf16 = feat16 + (size_t)n * 128;              // n*128 fp16
    float*  el     = (float*)(hbuf16 + (size_t)n * 128);    // n*4
    float*  er     = el + (size_t)n * 4;                    // n*4
    int*    cnt    = (int*)(er + (size_t)n * 4);            // n
    int*    offs   = cnt + n;                               // n+1
    int*    esrc   = offs + (n + 1);                        // NEDGES
    int*    bsum   = esrc + NEDGES;                         // 256
    int*    rank   = bsum + 256;                            // NEDGES
    __half* wt     = (__half*)(rank + NEDGES);              // 40960 halfs
    __half* wt1 = wt, *wt2 = wt + 16384, *wt3 = wt + 32768;

    const int gemmBlocks = (n + 63) / 64;                   // 782
    const int nBlk = (n + 255) / 256;                       // 196
    const int eBlk = (NEDGES + 255) / 256;
    const int aggBlk = 2048;

    // ---------- zero counters + W transposes ----------
    hipMemsetAsync(cnt, 0, (size_t)n * sizeof(int), stream);
    wtrans_k<<<160, 256, 0, stream>>>(W1, W2, W3, wt);

    // ---------- layer-1 GEMM with fused edge histogram ----------
    gemm_mfma_k<128, 4, false, true><<<gemmBlocks + HISTB, 256, 0, stream>>>(
        h, wt1, al1, ar1, feat16, el, er, n, gemmBlocks, dst, cnt, rank);

    // ---------- CSR scan + scatter ----------
    scan_blk_k<<<nBlk, 256, 0, stream>>>(cnt, offs, bsum, n);
    scan_addtop_k<<<nBlk, 256, 0, stream>>>(offs, bsum, n, nBlk);
    scatter_k<<<eBlk, 256, 0, stream>>>(src, dst, rank, offs, esrc);

    // ---------- layer 1 aggregate ----------
    node_agg4_k<<<aggBlk, 256, 0, stream>>>(offs, esrc, el, er, feat16, b1, hbuf16);

    // ---------- layer 2: 128 -> 4 heads x 32, relu ----------
    gemm_mfma_k<128, 4, true, false><<<gemmBlocks, 256, 0, stream>>>(
        hbuf16, wt2, al2, ar2, feat16, el, er, n, gemmBlocks, nullptr, nullptr, nullptr);
    node_agg4_k<<<aggBlk, 256, 0, stream>>>(offs, esrc, el, er, feat16, b2, hbuf16);

    // ---------- layer 3: 128 -> 1 head x 64, no relu ----------
    gemm_mfma_k<64, 1, true, false><<<gemmBlocks, 256, 0, stream>>>(
        hbuf16, wt3, al3, ar3, feat16, el, er, n, gemmBlocks, nullptr, nullptr, nullptr);
    node_agg1_k<<<aggBlk, 256, 0, stream>>>(offs, esrc, el, er, feat16, b3, out);
}

// Round 12
// 217.191 us; speedup vs baseline: 17.5327x; 1.0180x over previous
//
#include <hip/hip_runtime.h>
#include <hip/hip_fp16.h>

#define NNODES 50000
#define NEDGES 800000
#define HISTB 256   // extra blocks fused into gemm1 for the histogram

__device__ __forceinline__ float leaky(float x) { return x >= 0.f ? x : 0.2f * x; }

typedef _Float16 f16x8 __attribute__((ext_vector_type(8)));
typedef float f32x4 __attribute__((ext_vector_type(4)));

struct __align__(8)  half4v { __half2 h0, h1; };
struct __align__(16) half8v { __half2 h0, h1, h2, h3; };

// ---- W transpose/convert: Wt[col][k] fp16 for all three layers -------------
__global__ __launch_bounds__(256) void wtrans_k(const float* __restrict__ W1,
                                                const float* __restrict__ W2,
                                                const float* __restrict__ W3,
                                                __half* __restrict__ Wt) {
    int i = blockIdx.x * 256 + threadIdx.x;
    if (i < 16384) {                       // W1: [128][128]
        int k = i >> 7, c = i & 127;
        Wt[c * 128 + k] = __float2half_rn(W1[i]);
    } else if (i < 32768) {                // W2: [128][128]
        int e = i - 16384, k = e >> 7, c = e & 127;
        Wt[16384 + c * 128 + k] = __float2half_rn(W2[e]);
    } else if (i < 40960) {                // W3: [128][64]
        int e = i - 32768, k = e >> 6, c = e & 63;
        Wt[32768 + c * 128 + k] = __float2half_rn(W3[e]);
    }
}

// ---- MFMA GEMM + fused attention dots (+ optional histogram) ---------------
// Yh[n x F] (fp16) = X[n x 128] @ W[128 x F] via v_mfma_f32_16x16x32_f16.
// A-fragments direct from global X; B-fragments from pre-transposed global Wt
// (L1/L2-resident). C-tile staged through LDS for coalesced 16B stores.
template<int F, int H, bool FP16IN, bool DO_HIST>
__global__ __launch_bounds__(256) void gemm_mfma_k(const void* __restrict__ Xv,
                                                   const __half* __restrict__ Wt,
                                                   const float* __restrict__ al,
                                                   const float* __restrict__ ar,
                                                   __half* __restrict__ Yh,
                                                   float* __restrict__ el,
                                                   float* __restrict__ er, int n,
                                                   int nGemm,
                                                   const int* __restrict__ dst,
                                                   int* __restrict__ cnt,
                                                   int* __restrict__ rank) {
    constexpr int K = 128;
    constexpr int NT = F / 16;
    constexpr int LDC = F + 8;           // halfs; pad to spread banks

    if (DO_HIST && blockIdx.x >= nGemm) {
        int b = blockIdx.x - nGemm;
        for (int e = b * 256 + threadIdx.x; e < NEDGES; e += HISTB * 256)
            rank[e] = atomicAdd(&cnt[dst[e]], 1);
        return;
    }

    __shared__ __align__(16) __half Cs[64 * LDC];

    const int tid = threadIdx.x;
    const int wv = tid >> 6, lane = tid & 63;
    const int cl = lane & 15, kg = lane >> 4;
    const int r0 = blockIdx.x * 64;
    const int rowA = r0 + 16 * wv + cl;
    const int rA = rowA < n ? rowA : n - 1;     // clamped load row (stores guarded)

    f32x4 acc[NT];
    #pragma unroll
    for (int t = 0; t < NT; t++) acc[t] = (f32x4){0.f, 0.f, 0.f, 0.f};

    #pragma unroll
    for (int ks = 0; ks < K / 32; ks++) {
        f16x8 a;
        if constexpr (FP16IN) {
            a = *(const f16x8*)((const __half*)Xv + (size_t)rA * K + ks * 32 + kg * 8);
        } else {
            const float* Xp = (const float*)Xv + (size_t)rA * K + ks * 32 + kg * 8;
            float4 x0 = *(const float4*)Xp;
            float4 x1 = *(const float4*)(Xp + 4);
            a[0] = (_Float16)x0.x; a[1] = (_Float16)x0.y;
            a[2] = (_Float16)x0.z; a[3] = (_Float16)x0.w;
            a[4] = (_Float16)x1.x; a[5] = (_Float16)x1.y;
            a[6] = (_Float16)x1.z; a[7] = (_Float16)x1.w;
        }
        #pragma unroll
        for (int t = 0; t < NT; t++) {
            f16x8 b = *(const f16x8*)(Wt + (size_t)(16 * t + cl) * K + ks * 32 + kg * 8);
            acc[t] = __builtin_amdgcn_mfma_f32_16x16x32_f16(a, b, acc[t], 0, 0, 0);
        }
    }

    // C layout col=lane&15, row=(lane>>4)*4+j [m89] -> LDS -> coalesced stores
    #pragma unroll
    for (int t = 0; t < NT; t++)
        #pragma unroll
        for (int j = 0; j < 4; j++)
            Cs[(16 * wv + 4 * kg + j) * LDC + 16 * t + cl] = __float2half_rn(acc[t][j]);
    __syncthreads();
    {
        constexpr int SEGS = F / 8;            // 16B segments per row
        constexpr int RPS = 256 / SEGS;        // rows per sweep
        #pragma unroll
        for (int s = 0; s < 64 / RPS; s++) {
            int idx = s * 256 + tid;
            int row = idx / SEGS, seg = idx % SEGS;
            int grow = r0 + row;
            if (grow < n)
                *(half8v*)&Yh[(size_t)grow * F + seg * 8] =
                    *(const half8v*)&Cs[row * LDC + seg * 8];
        }
    }

    // fused attention dots from f32 accumulators
    float alv[NT], arv[NT];
    #pragma unroll
    for (int t = 0; t < NT; t++) { alv[t] = al[16 * t + cl]; arv[t] = ar[16 * t + cl]; }

    if (H == 1) {
        float pl[4], pr[4];
        #pragma unroll
        for (int j = 0; j < 4; j++) {
            pl[j] = 0.f; pr[j] = 0.f;
            #pragma unroll
            for (int t = 0; t < NT; t++) { pl[j] += acc[t][j] * alv[t]; pr[j] += acc[t][j] * arv[t]; }
        }
        #pragma unroll
        for (int off = 1; off < 16; off <<= 1)
            #pragma unroll
            for (int j = 0; j < 4; j++) { pl[j] += __shfl_xor(pl[j], off); pr[j] += __shfl_xor(pr[j], off); }
        if (cl == 0)
            #pragma unroll
            for (int j = 0; j < 4; j++) {
                int row = r0 + 16 * wv + 4 * kg + j;
                if (row < n) { el[row] = pl[j]; er[row] = pr[j]; }
            }
    } else {
        float pl[4][4], pr[4][4];          // [head][j]
        #pragma unroll
        for (int hh = 0; hh < 4; hh++)
            #pragma unroll
            for (int j = 0; j < 4; j++) {
                pl[hh][j] = acc[2 * hh][j] * alv[2 * hh] + acc[2 * hh + 1][j] * alv[2 * hh + 1];
                pr[hh][j] = acc[2 * hh][j] * arv[2 * hh] + acc[2 * hh + 1][j] * arv[2 * hh + 1];
            }
        #pragma unroll
        for (int off = 1; off < 16; off <<= 1)
            #pragma unroll
            for (int hh = 0; hh < 4; hh++)
                #pragma unroll
                for (int j = 0; j < 4; j++) {
                    pl[hh][j] += __shfl_xor(pl[hh][j], off);
                    pr[hh][j] += __shfl_xor(pr[hh][j], off);
                }
        if (cl == 0)
            #pragma unroll
            for (int j = 0; j < 4; j++) {
                int row = r0 + 16 * wv + 4 * kg + j;
                if (row < n)
                    #pragma unroll
                    for (int hh = 0; hh < 4; hh++) {
                        el[row * 4 + hh] = pl[hh][j];
                        er[row * 4 + hh] = pr[hh][j];
                    }
            }
    }
}

// ---------------- CSR scan kernels ------------------------------------------
__global__ void scan_blk_k(const int* __restrict__ cnt, int* __restrict__ offs,
                           int* __restrict__ bsum, int n) {
    __shared__ int sm[256];
    int tid = threadIdx.x;
    int i = blockIdx.x * 256 + tid;
    int v = (i < n) ? cnt[i] : 0;
    sm[tid] = v;
    __syncthreads();
    for (int off = 1; off < 256; off <<= 1) {
        int t = (tid >= off) ? sm[tid - off] : 0;
        __syncthreads();
        sm[tid] += t;
        __syncthreads();
    }
    if (i < n) offs[i] = sm[tid] - v;
    if (tid == 255) bsum[blockIdx.x] = sm[255];
}

__global__ void scan_addtop_k(int* __restrict__ offs, const int* __restrict__ bsum,
                              int n, int nb) {
    __shared__ int sm[256];
    int tid = threadIdx.x;
    int v = (tid < nb) ? bsum[tid] : 0;
    sm[tid] = v;
    __syncthreads();
    for (int off = 1; off < 256; off <<= 1) {
        int t = (tid >= off) ? sm[tid - off] : 0;
        __syncthreads();
        sm[tid] += t;
        __syncthreads();
    }
    int prefix = (blockIdx.x > 0) ? sm[blockIdx.x - 1] : 0;
    int i = blockIdx.x * 256 + tid;
    if (i < n) offs[i] += prefix;
    if (i == 0) offs[n] = NEDGES;
}

__global__ void scatter_k(const int* __restrict__ src, const int* __restrict__ dst,
                          const int* __restrict__ rank, const int* __restrict__ offs,
                          int* __restrict__ esrc) {
    int e = blockIdx.x * blockDim.x + threadIdx.x;
    if (e < NEDGES) esrc[offs[dst[e]] + rank[e]] = src[e];
}

// ---------------- fused single-pass softmax+aggregate, H=4 D=32 ------------
__global__ __launch_bounds__(256) void node_agg4_k(const int* __restrict__ offs,
                                                   const int* __restrict__ esrc,
                                                   const float* __restrict__ el,
                                                   const float* __restrict__ er,
                                                   const __half* __restrict__ feat,
                                                   const float* __restrict__ bias,
                                                   __half* __restrict__ out) {
    const int lane = threadIdx.x & 63;
    const int gw0 = (blockIdx.x * 256 + threadIdx.x) >> 6;
    const int NW = (gridDim.x * 256) >> 6;

    const int h  = lane & 3;
    const int q  = lane >> 4;
    const int cl = lane & 15;
    const int hd = cl >> 2;

    float4 ba = *(const float4*)&bias[8 * cl];
    float4 bb = *(const float4*)&bias[8 * cl + 4];

    for (int wid = gw0; wid < NNODES; wid += NW) {
        int beg = offs[wid], end = offs[wid + 1];
        float erh = er[wid * 4 + h];

        float acc[8] = {0.f, 0.f, 0.f, 0.f, 0.f, 0.f, 0.f, 0.f};
        float dsum = 0.f;
        for (int base = beg; base < end; base += 16) {
            int rem = end - base;
            if (rem > 16) rem = 16;
            int sv = 0;
            if (lane < rem) sv = esrc[base + lane];
            int se = __shfl(sv, lane >> 2);
            float p = 0.f;
            if ((lane >> 2) < rem)
                p = __expf(leaky(el[se * 4 + h] + erh));
            dsum += p;
            #pragma unroll
            for (int e = 0; e < 16 && e < rem; e += 4) {
                int eidx = e + q;
                int s = __shfl(sv, eidx);
                float a = __shfl(p, eidx * 4 + hd);
                half8v hv = *(const half8v*)&feat[(size_t)s * 128 + 8 * cl];
                float2 f0 = __half22float2(hv.h0);
                float2 f1 = __half22float2(hv.h1);
                float2 f2 = __half22float2(hv.h2);
                float2 f3 = __half22float2(hv.h3);
                acc[0] += f0.x * a; acc[1] += f0.y * a;
                acc[2] += f1.x * a; acc[3] += f1.y * a;
                acc[4] += f2.x * a; acc[5] += f2.y * a;
                acc[6] += f3.x * a; acc[7] += f3.y * a;
            }
        }
        #pragma unroll
        for (int c = 0; c < 8; c++) {
            acc[c] += __shfl_xor(acc[c], 16);
            acc[c] += __shfl_xor(acc[c], 32);
        }
        #pragma unroll
        for (int off = 4; off < 64; off <<= 1) dsum += __shfl_xor(dsum, off);
        float dh = __shfl(dsum, hd);
        float inv = dh > 0.f ? 1.f / dh : 0.f;
        if (q == 0) {
            float v0 = fmaxf(acc[0] * inv + ba.x, 0.f), v1 = fmaxf(acc[1] * inv + ba.y, 0.f);
            float v2 = fmaxf(acc[2] * inv + ba.z, 0.f), v3 = fmaxf(acc[3] * inv + ba.w, 0.f);
            float v4 = fmaxf(acc[4] * inv + bb.x, 0.f), v5 = fmaxf(acc[5] * inv + bb.y, 0.f);
            float v6 = fmaxf(acc[6] * inv + bb.z, 0.f), v7 = fmaxf(acc[7] * inv + bb.w, 0.f);
            half8v hv;
            hv.h0 = __halves2half2(__float2half_rn(v0), __float2half_rn(v1));
            hv.h1 = __halves2half2(__float2half_rn(v2), __float2half_rn(v3));
            hv.h2 = __halves2half2(__float2half_rn(v4), __float2half_rn(v5));
            hv.h3 = __halves2half2(__float2half_rn(v6), __float2half_rn(v7));
            *(half8v*)&out[(size_t)wid * 128 + 8 * cl] = hv;
        }
    }
}

// ---------------- fused single-pass softmax+aggregate, H=1 D=64 ------------
__global__ __launch_bounds__(256) void node_agg1_k(const int* __restrict__ offs,
                                                   const int* __restrict__ esrc,
                                                   const float* __restrict__ el,
                                                   const float* __restrict__ er,
                                                   const __half* __restrict__ feat,
                                                   const float* __restrict__ bias,
                                                   float* __restrict__ out) {
    const int lane = threadIdx.x & 63;
    const int gw0 = (blockIdx.x * 256 + threadIdx.x) >> 6;
    const int NW = (gridDim.x * 256) >> 6;

    const int q  = lane >> 4;
    const int cl = lane & 15;
    float4 b4 = *(const float4*)&bias[4 * cl];

    for (int wid = gw0; wid < NNODES; wid += NW) {
        int beg = offs[wid], end = offs[wid + 1];
        float erd = er[wid];

        float acc[4] = {0.f, 0.f, 0.f, 0.f};
        float dsum = 0.f;
        for (int base = beg; base < end; base += 64) {
            int rem = end - base;
            if (rem > 64) rem = 64;
            int sv = 0;
            float p = 0.f;
            if (lane < rem) {
                sv = esrc[base + lane];
                p = __expf(leaky(el[sv] + erd));
            }
            dsum += p;
            #pragma unroll 4
            for (int e = 0; e < rem; e += 4) {
                int eidx = e + q;
                int s = __shfl(sv, eidx);
                float a = __shfl(p, eidx);
                half4v hv = *(const half4v*)&feat[(size_t)s * 64 + 4 * cl];
                float2 f0 = __half22float2(hv.h0);
                float2 f1 = __half22float2(hv.h1);
                acc[0] += f0.x * a; acc[1] += f0.y * a;
                acc[2] += f1.x * a; acc[3] += f1.y * a;
            }
        }
        #pragma unroll
        for (int c = 0; c < 4; c++) {
            acc[c] += __shfl_xor(acc[c], 16);
            acc[c] += __shfl_xor(acc[c], 32);
        }
        #pragma unroll
        for (int off = 1; off < 64; off <<= 1) dsum += __shfl_xor(dsum, off);
        float inv = dsum > 0.f ? 1.f / dsum : 0.f;
        if (q == 0) {
            *(float4*)&out[(size_t)wid * 64 + 4 * cl] =
                make_float4(acc[0] * inv + b4.x, acc[1] * inv + b4.y,
                            acc[2] * inv + b4.z, acc[3] * inv + b4.w);
        }
    }
}

extern "C" void kernel_launch(void* const* d_in, const int* in_sizes, int n_in,
                              void* d_out, int out_size, void* d_ws, size_t ws_size,
                              hipStream_t stream) {
    const float* h   = (const float*)d_in[0];
    const int*   src = (const int*)d_in[1];
    const int*   dst = (const int*)d_in[2];
    const float* W1  = (const float*)d_in[3];
    const float* al1 = (const float*)d_in[4];
    const float* ar1 = (const float*)d_in[5];
    const float* b1  = (const float*)d_in[6];
    const float* W2  = (const float*)d_in[7];
    const float* al2 = (const float*)d_in[8];
    const float* ar2 = (const float*)d_in[9];
    const float* b2  = (const float*)d_in[10];
    const float* W3  = (const float*)d_in[11];
    const float* al3 = (const float*)d_in[12];
    const float* ar3 = (const float*)d_in[13];
    const float* b3  = (const float*)d_in[14];
    float* out = (float*)d_out;

    const int n = NNODES;
    __half* feat16 = (__half*)d_ws;                         // n*128 fp16
    __half* hbuf16 = feat16 + (size_t)n * 128;              // n*128 fp16
    float*  el     = (float*)(hbuf16 + (size_t)n * 128);    // n*4
    float*  er     = el + (size_t)n * 4;                    // n*4
    int*    cnt    = (int*)(er + (size_t)n * 4);            // n
    int*    offs   = cnt + n;                               // n+1
    int*    esrc   = offs + (n + 1);                        // NEDGES
    int*    bsum   = esrc + NEDGES;                         // 256
    int*    rank   = bsum + 256;                            // NEDGES
    __half* wt     = (__half*)(rank + NEDGES);              // 40960 halfs
    __half* wt1 = wt, *wt2 = wt + 16384, *wt3 = wt + 32768;

    const int gemmBlocks = (n + 63) / 64;                   // 782
    const int nBlk = (n + 255) / 256;                       // 196
    const int eBlk = (NEDGES + 255) / 256;
    const int aggBlk = 2048;

    // ---------- zero counters + W transposes ----------
    hipMemsetAsync(cnt, 0, (size_t)n * sizeof(int), stream);
    wtrans_k<<<160, 256, 0, stream>>>(W1, W2, W3, wt);

    // ---------- layer-1 GEMM with fused edge histogram ----------
    gemm_mfma_k<128, 4, false, true><<<gemmBlocks + HISTB, 256, 0, stream>>>(
        h, wt1, al1, ar1, feat16, el, er, n, gemmBlocks, dst, cnt, rank);

    // ---------- CSR scan + scatter ----------
    scan_blk_k<<<nBlk, 256, 0, stream>>>(cnt, offs, bsum, n);
    scan_addtop_k<<<nBlk, 256, 0, stream>>>(offs, bsum, n, nBlk);
    scatter_k<<<eBlk, 256, 0, stream>>>(src, dst, rank, offs, esrc);

    // ---------- layer 1 aggregate ----------
    node_agg4_k<<<aggBlk, 256, 0, stream>>>(offs, esrc, el, er, feat16, b1, hbuf16);

    // ---------- layer 2: 128 -> 4 heads x 32, relu ----------
    gemm_mfma_k<128, 4, true, false><<<gemmBlocks, 256, 0, stream>>>(
        hbuf16, wt2, al2, ar2, feat16, el, er, n, gemmBlocks, nullptr, nullptr, nullptr);
    node_agg4_k<<<aggBlk, 256, 0, stream>>>(offs, esrc, el, er, feat16, b2, hbuf16);

    // ---------- layer 3: 128 -> 1 head x 64, no relu ----------
    gemm_mfma_k<64, 1, true, false><<<gemmBlocks, 256, 0, stream>>>(
        hbuf16, wt3, al3, ar3, feat16, el, er, n, gemmBlocks, nullptr, nullptr, nullptr);
    node_agg1_k<<<aggBlk, 256, 0, stream>>>(offs, esrc, el, er, feat16, b3, out);
}